// Round 11
// baseline (156.599 us; speedup 1.0000x reference)
//
#include <hip/hip_runtime.h>
#include <hip/hip_bf16.h>

#define NB 32
#define NP 2048
#define NS 64
#define NK 128

// d_out layout (FLOAT32 elements)
#define MEAN_OFF 0
#define STD_OFF  1048576
#define XIDX_OFF 2097152
#define YIDX_OFF 2359296

#define GA_LD 576   // gA bf16 leading dim (515 padded)

typedef __attribute__((ext_vector_type(4)))  short s4;
typedef __attribute__((ext_vector_type(8)))  short short8;
typedef __attribute__((ext_vector_type(16))) float f32x16;

static __device__ __forceinline__ float leaky(float x){ return x >= 0.0f ? x : 0.2f * x; }

static __device__ __forceinline__ unsigned short bf16u(float v){
    __hip_bfloat16 h = __float2bfloat16(v);
    return *(unsigned short*)&h;
}

static __device__ __forceinline__ unsigned cvtpk(float a, float b){
    unsigned d;
    asm("v_cvt_pk_bf16_f32 %0, %1, %2" : "=v"(d) : "v"(a), "v"(b));
    return d;
}
static __device__ __forceinline__ void plswap(unsigned &a, unsigned &b){
    asm volatile("v_permlane32_swap_b32 %0, %1" : "+v"(a), "+v"(b));
}

// strict IEEE fp32, no contraction — matches numpy/jax op order
static __device__ __forceinline__ float d2s(float ax,float ay,float az,float bx,float by,float bz){
    float dx = __fsub_rn(ax,bx), dy = __fsub_rn(ay,by), dz = __fsub_rn(az,bz);
    return __fadd_rn(__fadd_rn(__fmul_rn(dx,dx),__fmul_rn(dy,dy)),__fmul_rn(dz,dz));
}

// ---------------- FPS (blocks 0..31) + coalesced tiled weight prep (blocks 32..248) ----------------
// Prep tiles (64x64, LDS [64][65] transpose):
//   tb <  72 : W4 [k<515][512 n] -> W4T[n][576] (zero pad)    kt=tb>>3 (0..8), nt=tb&7
//   tb < 200 : W5 [512 k][1024 n] -> W5T[n][512]              q=tb-72, kt=q>>4, nt=q&15
//   tb < 216 : W3 [128 i][512 c] -> W3T swz byte(c,i)=c*256+((i*2)^((c&15)<<4))
//   tb == 216: W2 [64 j][128 i] -> W2T[i][j]
__global__ __launch_bounds__(256) void fps_prep_kernel(const float* __restrict__ pos,
                                                       float* __restrict__ centersWs,
                                                       const float* __restrict__ W2,
                                                       const float* __restrict__ W3,
                                                       const float* __restrict__ W4,
                                                       const float* __restrict__ W5,
                                                       __hip_bfloat16* __restrict__ W2T,
                                                       __hip_bfloat16* __restrict__ W3T,
                                                       __hip_bfloat16* __restrict__ W4T,
                                                       __hip_bfloat16* __restrict__ W5T)
{
    if (blockIdx.x >= NB) {
        __shared__ float tl[64][65];
        int tb = blockIdx.x - NB;       // 0..216
        int t = threadIdx.x;
        int tr = t >> 6;                // 0..3
        int tc = t & 63;
        if (tb < 72) {
            int kt = tb >> 3, nt = tb & 7;
            int k0 = kt*64, n0 = nt*64;
            #pragma unroll
            for (int it = 0; it < 16; it++) {
                int k = k0 + tr + it*4;
                tl[tr + it*4][tc] = (k < 515) ? W4[(size_t)k*512 + n0 + tc] : 0.0f;
            }
            __syncthreads();
            #pragma unroll
            for (int it = 0; it < 16; it++) {
                int nl = tr + it*4;
                W4T[(size_t)(n0 + nl)*GA_LD + k0 + tc] = __float2bfloat16(tl[tc][nl]);
            }
        } else if (tb < 200) {
            int q = tb - 72;
            int kt = q >> 4, nt = q & 15;
            int k0 = kt*64, n0 = nt*64;
            #pragma unroll
            for (int it = 0; it < 16; it++)
                tl[tr + it*4][tc] = W5[(size_t)(k0 + tr + it*4)*1024 + n0 + tc];
            __syncthreads();
            #pragma unroll
            for (int it = 0; it < 16; it++) {
                int nl = tr + it*4;
                W5T[(size_t)(n0 + nl)*512 + k0 + tc] = __float2bfloat16(tl[tc][nl]);
            }
        } else if (tb < 216) {
            int q = tb - 200;
            int i0 = (q >> 3)*64, c0 = (q & 7)*64;
            #pragma unroll
            for (int it = 0; it < 16; it++)
                tl[tr + it*4][tc] = W3[(size_t)(i0 + tr + it*4)*512 + c0 + tc];
            __syncthreads();
            #pragma unroll
            for (int it = 0; it < 16; it++) {
                int c = c0 + tr + it*4;
                int i = i0 + tc;
                int byte = c*256 + ((i*2) ^ ((c&15)<<4));
                *(unsigned short*)((char*)W3T + byte) = bf16u(tl[tc][tr + it*4]);
            }
        } else {
            for (int e = t; e < 8192; e += 256) {
                int i = e & 127, j = e >> 7;      // coalesced read over i
                W2T[i*64 + j] = __float2bfloat16(W2[(size_t)j*128 + i]);
            }
        }
        return;
    }

    // ---- FPS path: 256 threads, one barrier/step, xyz carried through reduce,
    //      centers buffered in LDS (no global store in the serial loop)
    int b = blockIdx.x;
    int t = threadIdx.x;
    __shared__ float px[NP], py[NP], pz[NP];
    __shared__ float redv[2][4], redx[2][4], redy[2][4], redz[2][4];
    __shared__ int   redi[2][4];
    __shared__ float cbuf[NS*3];

    const float* pb = pos + (size_t)b * NP * 3;
    for (int n = t; n < NP; n += 256) {
        px[n] = pb[n*3+0]; py[n] = pb[n*3+1]; pz[n] = pb[n*3+2];
    }
    __syncthreads();

    float p0x = px[0], p0y = py[0], p0z = pz[0];
    if (t == 0) { cbuf[0] = p0x; cbuf[1] = p0y; cbuf[2] = p0z; }

    float dl[8];
    float bv = -1.0f; int bi = 0;
    #pragma unroll
    for (int q = 0; q < 8; q++) {
        int n = t + q*256;
        dl[q] = d2s(px[n],py[n],pz[n], p0x,p0y,p0z);
        if (dl[q] > bv) { bv = dl[q]; bi = n; }
    }
    float lx = px[bi], ly = py[bi], lz = pz[bi];

    int w = t >> 6;
    for (int s = 1; s < NS; s++) {
        // wave butterfly over (v,i,x,y,z), min-index on equal
        #pragma unroll
        for (int m = 32; m > 0; m >>= 1) {
            float ov = __shfl_xor(bv, m);
            int   oi = __shfl_xor(bi, m);
            float ox = __shfl_xor(lx, m);
            float oy = __shfl_xor(ly, m);
            float oz = __shfl_xor(lz, m);
            if (ov > bv || (ov == bv && oi < bi)) { bv = ov; bi = oi; lx = ox; ly = oy; lz = oz; }
        }
        int s1 = s & 1;
        if ((t & 63) == 0) {
            redv[s1][w] = bv; redi[s1][w] = bi;
            redx[s1][w] = lx; redy[s1][w] = ly; redz[s1][w] = lz;
        }
        __syncthreads();
        float v = redv[s1][0]; int j = redi[s1][0];
        float cx = redx[s1][0], cy = redy[s1][0], cz = redz[s1][0];
        #pragma unroll
        for (int k = 1; k < 4; k++) {
            if (redv[s1][k] > v || (redv[s1][k] == v && redi[s1][k] < j)) {
                v = redv[s1][k]; j = redi[s1][k];
                cx = redx[s1][k]; cy = redy[s1][k]; cz = redz[s1][k];
            }
        }
        if (t == 0) { cbuf[s*3+0] = cx; cbuf[s*3+1] = cy; cbuf[s*3+2] = cz; }
        // fused update + local argmax
        bv = -1.0f; bi = 0;
        #pragma unroll
        for (int q = 0; q < 8; q++) {
            int n = t + q*256;
            float nd = fminf(dl[q], d2s(px[n],py[n],pz[n], cx,cy,cz));
            dl[q] = nd;
            if (nd > bv) { bv = nd; bi = n; }
        }
        lx = px[bi]; ly = py[bi]; lz = pz[bi];
    }
    __syncthreads();
    for (int e = t; e < NS*3; e += 256)
        centersWs[(size_t)b*NS*3 + e] = cbuf[e];
}

// ---------------- fused ball query + MLP(3->64->128->512) + masked max, no-h2s ----------------
// LDS map (37392 B):
//   @0     16 KB : layer1 h1s [k][j] swz (k&7)<<4; layer3 bufs for chunks t%4==2 (@0), t%4==3 (@8192)
//   @16384 16 KB : layer3 bufs for chunks t%4==0 (@16384), t%4==1 (@24576); redf[4][512] @16384 after loop
//   @32768 2 KB  : nbL int[4][128]  (scan)  /  relL f32[128][4] (after)
//   @34816 512 B : b2s
//   @35328 2 KB  : b3s
//   @37376 16 B  : cntW4
__global__ __launch_bounds__(256, 4) void ball_mlp_kernel(
    const float* __restrict__ pos,
    const float* __restrict__ W1, const float* __restrict__ b1,
    const float* __restrict__ b2, const float* __restrict__ b3,
    const __hip_bfloat16* __restrict__ W2Tp,
    const __hip_bfloat16* __restrict__ W3Tp,
    const float* __restrict__ centersWs,
    float* __restrict__ out,
    __hip_bfloat16* __restrict__ gAb)
{
    __shared__ char smem[37392];
    char*  h1s  = smem;
    float* relL = (float*)(smem + 32768);
    int*   nbL  = (int*)(smem + 32768);
    float* b2s  = (float*)(smem + 34816);
    float* b3s  = (float*)(smem + 35328);
    int*   cntW4= (int*)(smem + 37376);

    const short* W2T  = (const short*)W2Tp;
    const char*  W3Tb = (const char*)W3Tp;

    int r = blockIdx.x, b = r >> 6, tid = threadIdx.x;
    int l = tid & 63, w = tid >> 6;
    int l31 = l & 31;
    int hsel = l >> 5;
    int jsel8 = hsel * 8;
    int colsel = hsel * 16;

#define STAGE_W3(CH, DST)                                                                              \
    {                                                                                                  \
        const char* _s = W3Tb + (CH)*8192 + w*2048 + l*16;                                             \
        char* _d = (DST) + w*2048;                                                                     \
        __builtin_amdgcn_global_load_lds((const __attribute__((address_space(1))) void*)(_s),          \
                                         (__attribute__((address_space(3))) void*)(_d), 16, 0, 0);     \
        __builtin_amdgcn_global_load_lds((const __attribute__((address_space(1))) void*)(_s + 1024),   \
                                         (__attribute__((address_space(3))) void*)(_d + 1024), 16, 0, 0); \
    }

    // chunk t lives in buf at smem + 8192*((t+2)&3): chunks 0,1 -> dedicated region, stage NOW
    STAGE_W3(0, smem + 16384);
    STAGE_W3(1, smem + 24576);

    float cx = centersWs[r*3+0], cy = centersWs[r*3+1], cz = centersWs[r*3+2];

    // ---- ball query: wave w scans points [w*512, w*512+512), ordered compaction
    const float* pb = pos + (size_t)b * NP * 3;
    {
        int myCnt = 0;
        #pragma unroll
        for (int c = 0; c < 8; c++) {
            int n = w*512 + c*64 + l;
            float x = pb[n*3+0], y = pb[n*3+1], z = pb[n*3+2];
            bool in = d2s(cx,cy,cz, x,y,z) < 0.04f;
            unsigned long long m = __ballot(in);
            int before = __popcll(m & ((1ull << l) - 1ull));
            int p = myCnt + before;
            if (in && p < NK) nbL[w*NK + p] = n;
            myCnt += (int)__popcll(m);
        }
        if (l == 0) cntW4[w] = myCnt;
    }
    // stage b3 -> LDS while scan settles
    b3s[tid] = b3[tid];
    b3s[tid + 256] = b3[tid + 256];
    __syncthreads();

    int c0 = cntW4[0], c1 = cntW4[1], c2 = cntW4[2], c3 = cntW4[3];
    int cnt = c0 + c1 + c2 + c3;
    cnt = cnt > NK ? NK : cnt;

    int nv = 0;
    if (tid < NK) {
        bool valid = tid < cnt;
        int seg = 0, off = 0;
        if (tid >= c0)           { seg = 1; off = c0; }
        if (tid >= c0 + c1)      { seg = 2; off = c0 + c1; }
        if (tid >= c0 + c1 + c2) { seg = 3; off = c0 + c1 + c2; }
        if (valid) nv = nbL[seg*NK + (tid - off)];
        out[XIDX_OFF + r*NK + tid] = valid ? (float)(nv + b*NP) : -1.0f;
        out[YIDX_OFF + r*NK + tid] = valid ? (float)r : -1.0f;
    }
    __syncthreads();          // nbL reads complete before relL overwrite

    if (tid < NK) {
        const float* pp = pb + (size_t)nv*3;
        relL[tid*4+0] = pp[0] - cx;
        relL[tid*4+1] = pp[1] - cy;
        relL[tid*4+2] = pp[2] - cz;
        relL[tid*4+3] = 0.0f;
        b2s[tid] = b2[tid];
    }
    __syncthreads();

    // ---- layer 1 (VALU): h1[k][j] = leaky(rel[k]·W1[:,j] + b1[j])
    {
        int jg = (tid & 15) * 4;
        float4 w0 = *(const float4*)&W1[jg];
        float4 w1 = *(const float4*)&W1[64 + jg];
        float4 w2 = *(const float4*)&W1[128 + jg];
        float4 bb = *(const float4*)&b1[jg];
        #pragma unroll
        for (int e = 0; e < 8; e++) {
            int k = (tid >> 4) + e*16;
            float4 r4 = *(const float4*)&relL[k*4];
            s4 pk;
            pk[0] = (short)bf16u(leaky(bb.x + r4.x*w0.x + r4.y*w1.x + r4.z*w2.x));
            pk[1] = (short)bf16u(leaky(bb.y + r4.x*w0.y + r4.y*w1.y + r4.z*w2.y));
            pk[2] = (short)bf16u(leaky(bb.z + r4.x*w0.z + r4.y*w1.z + r4.z*w2.z));
            pk[3] = (short)bf16u(leaky(bb.w + r4.x*w0.w + r4.y*w1.w + r4.z*w2.w));
            *(s4*)(h1s + k*128 + ((jg*2) ^ ((k&7)<<4))) = pk;
        }
    }
    __syncthreads();

    // ---- layer 2 (MFMA): wave w computes D2[i][k] for ALL i, k = w*32 + l31.
    // C-regs repacked in-register (cvt_pk + permlane32_swap) into layer3 A-frags a3[8].
    short8 a3[8];
    {
        int kcol = w*32 + l31;
        short8 bh[4];
        #pragma unroll
        for (int ks = 0; ks < 4; ks++) {
            int bc = ks*32 + colsel;
            bh[ks] = *(short8*)(h1s + kcol*128 + (bc ^ ((kcol&7)<<4)));
        }
        #pragma unroll
        for (int it = 0; it < 4; it++) {
            short8 aWf[4];
            #pragma unroll
            for (int ks = 0; ks < 4; ks++)
                aWf[ks] = *(const short8*)(W2T + (it*32 + l31)*64 + ks*16 + jsel8);
            f32x16 acc;
            #pragma unroll
            for (int q = 0; q < 16; q++) acc[q] = 0.f;
            #pragma unroll
            for (int ks = 0; ks < 4; ks++)
                acc = __builtin_amdgcn_mfma_f32_32x32x16_bf16(aWf[ks], bh[ks], acc, 0, 0, 0);
            // bias + leaky: acc[reg] holds i = it*32 + 4*hsel + (reg&3) + 8*(reg>>2)
            int ibase = it*32 + 4*hsel;
            #pragma unroll
            for (int g = 0; g < 4; g++) {
                float4 bb = *(const float4*)&b2s[ibase + g*8];
                acc[g*4+0] = leaky(acc[g*4+0] + bb.x);
                acc[g*4+1] = leaky(acc[g*4+1] + bb.y);
                acc[g*4+2] = leaky(acc[g*4+2] + bb.z);
                acc[g*4+3] = leaky(acc[g*4+3] + bb.w);
            }
            // repack: regs hf*8+0..7 -> frag 2it+hf (i = (2it+hf)*16 + jsel8 + 0..7 per lane)
            #pragma unroll
            for (int hf = 0; hf < 2; hf++) {
                unsigned A0 = cvtpk(acc[hf*8+0], acc[hf*8+1]);
                unsigned A1 = cvtpk(acc[hf*8+2], acc[hf*8+3]);
                unsigned B0 = cvtpk(acc[hf*8+4], acc[hf*8+5]);
                unsigned B1 = cvtpk(acc[hf*8+6], acc[hf*8+7]);
                plswap(A0, B0);
                plswap(A1, B1);
                union { unsigned u[4]; short8 s; } f;
                f.u[0] = A0; f.u[1] = A1; f.u[2] = B0; f.u[3] = B1;
                a3[2*it + hf] = f.s;
            }
        }
    }
    __syncthreads();     // all h1s reads done -> h1s region becomes W3 bufs

    // stage chunks 2,3 into h1s region: (2+2)&3=0 -> @0, (3+2)&3=1 -> @8192
    STAGE_W3(2, smem);
    STAGE_W3(3, smem + 8192);

    // ---- layer 3: 16 chunks of 32 cols, 4-buffer pipeline, one barrier/chunk, max in regs
    int kb0 = w*32 + 4*hsel;
    float mred[16];
    #pragma unroll
    for (int t = 0; t < 16; t++) {
        if (t <= 13)      { asm volatile("s_waitcnt vmcnt(4)" ::: "memory"); }
        else if (t == 14) { asm volatile("s_waitcnt vmcnt(2)" ::: "memory"); }
        else              { asm volatile("s_waitcnt vmcnt(0)" ::: "memory"); }
        __builtin_amdgcn_sched_barrier(0);
        __builtin_amdgcn_s_barrier();
        __builtin_amdgcn_sched_barrier(0);

        if (t >= 1 && t + 3 < 16) {
            char* nbuf = smem + 8192*((t+1)&3);     // chunk t+3's buf = (t+5)&3 = (t+1)&3, freed at this barrier
            STAGE_W3(t+3, nbuf);
        }
        __builtin_amdgcn_sched_barrier(0);

        char* buf = smem + 8192*((t+2)&3);
        f32x16 acc;
        #pragma unroll
        for (int q = 0; q < 16; q++) acc[q] = 0.f;
        #pragma unroll
        for (int ks = 0; ks < 8; ks++) {
            int bc = ks*32 + colsel;
            short8 bv = *(short8*)(buf + l31*256 + (bc ^ ((l31&15)<<4)));
            acc = __builtin_amdgcn_mfma_f32_32x32x16_bf16(a3[ks], bv, acc, 0, 0, 0);
        }
        float m = -INFINITY;
        #pragma unroll
        for (int reg = 0; reg < 16; reg++) {
            int kloc = (reg&3) + 8*(reg>>2);
            if (kb0 + kloc < cnt) m = fmaxf(m, acc[reg]);
        }
        m = fmaxf(m, __shfl_xor(m, 32));
        mred[t] = m;
        __builtin_amdgcn_sched_barrier(0);
    }

    // ---- final: dump per-wave partials (bufs for chunks <=13 are dead), reduce, write gAb
    float* redf = (float*)(smem + 16384);
    if (l < 32) {
        #pragma unroll
        for (int t = 0; t < 16; t++)
            redf[w*512 + t*32 + l31] = mred[t];
    }
    __syncthreads();
    #pragma unroll
    for (int e = 0; e < 2; e++) {
        int c = tid + e*256;
        float m = fmaxf(fmaxf(redf[c], redf[512 + c]), fmaxf(redf[1024 + c], redf[1536 + c]));
        gAb[(size_t)r*GA_LD + c] = __float2bfloat16(leaky(m + b3s[c]));
    }
    if (tid < 64) {
        float v = 0.0f;
        if (tid == 0) v = cx; else if (tid == 1) v = cy; else if (tid == 2) v = cz;
        gAb[(size_t)r*GA_LD + 512 + tid] = __float2bfloat16(v);
    }
#undef STAGE_W3
}

// ---------------- FC1 (MFMA): g2b = leaky(gAb[2048,576] @ W4T' + b4), N=512 ----------------
__global__ __launch_bounds__(256) void fc1_kernel(const __hip_bfloat16* __restrict__ gAb,
                                                  const __hip_bfloat16* __restrict__ W4T,
                                                  const float* __restrict__ b4,
                                                  __hip_bfloat16* __restrict__ g2b)
{
    __shared__ char smem[16384];
    char* As = smem;            // [64 rows][64 k] bf16, swz ((row&7)<<4)
    char* Bs = smem + 8192;     // [64 cols][64 k] bf16, swz

    int bx = blockIdx.x & 7;    // N tile (512/64)
    int by = blockIdx.x >> 3;   // M tile (2048/64)
    int tid = threadIdx.x;
    int l = tid & 63, w = tid >> 6;
    int wm = w & 1, wn = w >> 1;
    int colsel = (l >> 5) * 16;

    f32x16 acc;
    #pragma unroll
    for (int q = 0; q < 16; q++) acc[q] = 0.f;

    int ra = wm*32 + (l & 31);
    int rn = wn*32 + (l & 31);

    for (int kb = 0; kb < GA_LD; kb += 64) {
        #pragma unroll
        for (int it = 0; it < 2; it++) {
            int e = it*256 + tid;            // 0..511
            int row = e >> 3, seg = e & 7;
            short8 va = *(const short8*)(gAb + (size_t)(by*64 + row)*GA_LD + kb + seg*8);
            *(short8*)(As + row*128 + ((seg*16) ^ ((row&7)<<4))) = va;
            short8 vb = *(const short8*)(W4T + (size_t)(bx*64 + row)*GA_LD + kb + seg*8);
            *(short8*)(Bs + row*128 + ((seg*16) ^ ((row&7)<<4))) = vb;
        }
        __syncthreads();
        #pragma unroll
        for (int ks = 0; ks < 4; ks++) {
            int bc = ks*32 + colsel;
            short8 av = *(short8*)(As + ra*128 + (bc ^ ((ra&7)<<4)));
            short8 bv = *(short8*)(Bs + rn*128 + (bc ^ ((rn&7)<<4)));
            acc = __builtin_amdgcn_mfma_f32_32x32x16_bf16(av, bv, acc, 0, 0, 0);
        }
        __syncthreads();
    }

    int col = bx*64 + wn*32 + (l & 31);
    float bcol = b4[col];
    int rbase = by*64 + wm*32 + 4*(l>>5);
    #pragma unroll
    for (int reg = 0; reg < 16; reg++) {
        int row = rbase + (reg&3) + 8*(reg>>2);
        g2b[(size_t)row*512 + col] = __float2bfloat16(leaky(acc[reg] + bcol));
    }
}

// ---------------- FC2 (MFMA): out = g2b @ W5T' + b5; mean | std=exp(0.5 lv) ----------------
__global__ __launch_bounds__(256) void fc2_kernel(const __hip_bfloat16* __restrict__ g2b,
                                                  const __hip_bfloat16* __restrict__ W5T,
                                                  const float* __restrict__ b5,
                                                  float* __restrict__ out)
{
    __shared__ char smem[16384];
    char* As = smem;
    char* Bs = smem + 8192;

    int bx = blockIdx.x & 15;   // N tile (1024/64)
    int by = blockIdx.x >> 4;   // M tile (2048/64)
    int tid = threadIdx.x;
    int l = tid & 63, w = tid >> 6;
    int wm = w & 1, wn = w >> 1;
    int colsel = (l >> 5) * 16;

    f32x16 acc;
    #pragma unroll
    for (int q = 0; q < 16; q++) acc[q] = 0.f;

    int ra = wm*32 + (l & 31);
    int rn = wn*32 + (l & 31);

    for (int kb = 0; kb < 512; kb += 64) {
        #pragma unroll
        for (int it = 0; it < 2; it++) {
            int e = it*256 + tid;
            int row = e >> 3, seg = e & 7;
            short8 va = *(const short8*)(g2b + (size_t)(by*64 + row)*512 + kb + seg*8);
            *(short8*)(As + row*128 + ((seg*16) ^ ((row&7)<<4))) = va;
            short8 vb = *(const short8*)(W5T + (size_t)(bx*64 + row)*512 + kb + seg*8);
            *(short8*)(Bs + row*128 + ((seg*16) ^ ((row&7)<<4))) = vb;
        }
        __syncthreads();
        #pragma unroll
        for (int ks = 0; ks < 4; ks++) {
            int bc = ks*32 + colsel;
            short8 av = *(short8*)(As + ra*128 + (bc ^ ((ra&7)<<4)));
            short8 bv = *(short8*)(Bs + rn*128 + (bc ^ ((rn&7)<<4)));
            acc = __builtin_amdgcn_mfma_f32_32x32x16_bf16(av, bv, acc, 0, 0, 0);
        }
        __syncthreads();
    }

    int col = bx*64 + wn*32 + (l & 31);
    float bcol = b5[col];
    int rbase = by*64 + wm*32 + 4*(l>>5);
    #pragma unroll
    for (int reg = 0; reg < 16; reg++) {
        int row = rbase + (reg&3) + 8*(reg>>2);
        float v = acc[reg] + bcol;
        if (col < 512) {
            out[MEAN_OFF + (size_t)row*512 + col] = v;
        } else {
            out[STD_OFF + (size_t)row*512 + (col - 512)] = expf(0.5f*v);
        }
    }
}

extern "C" void kernel_launch(void* const* d_in, const int* in_sizes, int n_in,
                              void* d_out, int out_size, void* d_ws, size_t ws_size,
                              hipStream_t stream) {
    const float* pos = (const float*)d_in[0];
    const float* W1  = (const float*)d_in[2];
    const float* b1  = (const float*)d_in[3];
    const float* W2  = (const float*)d_in[4];
    const float* b2  = (const float*)d_in[5];
    const float* W3  = (const float*)d_in[6];
    const float* b3  = (const float*)d_in[7];
    const float* W4  = (const float*)d_in[8];
    const float* b4  = (const float*)d_in[9];
    const float* W5  = (const float*)d_in[10];
    const float* b5  = (const float*)d_in[11];
    float* out = (float*)d_out;

    char* ws = (char*)d_ws;
    float* centersWs = (float*)(ws);                          // 24576 B
    __hip_bfloat16* gAb = (__hip_bfloat16*)(ws + 1081344);    // 2048*576*2 = 2359296
    __hip_bfloat16* g2b = (__hip_bfloat16*)(ws + 3440640);    // 2048*512*2 = 2097152
    __hip_bfloat16* W2T = (__hip_bfloat16*)(ws + 5537792);    // 16 KB
    __hip_bfloat16* W3T = (__hip_bfloat16*)(ws + 5554176);    // 128 KB
    __hip_bfloat16* W4T = (__hip_bfloat16*)(ws + 5685248);    // 576 KB
    __hip_bfloat16* W5T = (__hip_bfloat16*)(ws + 6275072);    // 1 MB -> ends 7323648

    hipLaunchKernelGGL(fps_prep_kernel, dim3(NB + 217), dim3(256), 0, stream,
                       pos, centersWs, W2, W3, W4, W5, W2T, W3T, W4T, W5T);
    hipLaunchKernelGGL(ball_mlp_kernel, dim3(NB*NS), dim3(256), 0, stream,
                       pos, W1,b1, b2,b3, W2T, W3T, centersWs, out, gAb);
    hipLaunchKernelGGL(fc1_kernel, dim3(256), dim3(256), 0, stream, gAb, W4T, b4, g2b);
    hipLaunchKernelGGL(fc2_kernel, dim3(512), dim3(256), 0, stream, g2b, W5T, b5, out);
}

// Round 12
// 146.499 us; speedup vs baseline: 1.0689x; 1.0689x over previous
//
#include <hip/hip_runtime.h>
#include <hip/hip_bf16.h>

#define NB 32
#define NP 2048
#define NS 64
#define NK 128

// d_out layout (FLOAT32 elements)
#define MEAN_OFF 0
#define STD_OFF  1048576
#define XIDX_OFF 2097152
#define YIDX_OFF 2359296

#define GA_LD 576   // gA bf16 leading dim (515 padded)

typedef __attribute__((ext_vector_type(4)))  short s4;
typedef __attribute__((ext_vector_type(8)))  short short8;
typedef __attribute__((ext_vector_type(16))) float f32x16;

static __device__ __forceinline__ float leaky(float x){ return x >= 0.0f ? x : 0.2f * x; }

static __device__ __forceinline__ unsigned short bf16u(float v){
    __hip_bfloat16 h = __float2bfloat16(v);
    return *(unsigned short*)&h;
}

static __device__ __forceinline__ unsigned cvtpk(float a, float b){
    unsigned d;
    asm("v_cvt_pk_bf16_f32 %0, %1, %2" : "=v"(d) : "v"(a), "v"(b));
    return d;
}
static __device__ __forceinline__ void plswap(unsigned &a, unsigned &b){
    asm volatile("v_permlane32_swap_b32 %0, %1" : "+v"(a), "+v"(b));
}

// strict IEEE fp32, no contraction — matches numpy/jax op order
static __device__ __forceinline__ float d2s(float ax,float ay,float az,float bx,float by,float bz){
    float dx = __fsub_rn(ax,bx), dy = __fsub_rn(ay,by), dz = __fsub_rn(az,bz);
    return __fadd_rn(__fadd_rn(__fmul_rn(dx,dx),__fmul_rn(dy,dy)),__fmul_rn(dz,dz));
}

// ---------------- FPS (blocks 0..31) + coalesced tiled weight prep (blocks 32..248) ----------------
__global__ __launch_bounds__(256) void fps_prep_kernel(const float* __restrict__ pos,
                                                       float* __restrict__ centersWs,
                                                       const float* __restrict__ W2,
                                                       const float* __restrict__ W3,
                                                       const float* __restrict__ W4,
                                                       const float* __restrict__ W5,
                                                       __hip_bfloat16* __restrict__ W2T,
                                                       __hip_bfloat16* __restrict__ W3T,
                                                       __hip_bfloat16* __restrict__ W4T,
                                                       __hip_bfloat16* __restrict__ W5T)
{
    if (blockIdx.x >= NB) {
        __shared__ float tl[64][65];
        int tb = blockIdx.x - NB;       // 0..216
        int t = threadIdx.x;
        int tr = t >> 6;                // 0..3
        int tc = t & 63;
        if (tb < 72) {
            int kt = tb >> 3, nt = tb & 7;
            int k0 = kt*64, n0 = nt*64;
            #pragma unroll
            for (int it = 0; it < 16; it++) {
                int k = k0 + tr + it*4;
                tl[tr + it*4][tc] = (k < 515) ? W4[(size_t)k*512 + n0 + tc] : 0.0f;
            }
            __syncthreads();
            #pragma unroll
            for (int it = 0; it < 16; it++) {
                int nl = tr + it*4;
                W4T[(size_t)(n0 + nl)*GA_LD + k0 + tc] = __float2bfloat16(tl[tc][nl]);
            }
        } else if (tb < 200) {
            int q = tb - 72;
            int kt = q >> 4, nt = q & 15;
            int k0 = kt*64, n0 = nt*64;
            #pragma unroll
            for (int it = 0; it < 16; it++)
                tl[tr + it*4][tc] = W5[(size_t)(k0 + tr + it*4)*1024 + n0 + tc];
            __syncthreads();
            #pragma unroll
            for (int it = 0; it < 16; it++) {
                int nl = tr + it*4;
                W5T[(size_t)(n0 + nl)*512 + k0 + tc] = __float2bfloat16(tl[tc][nl]);
            }
        } else if (tb < 216) {
            int q = tb - 200;
            int i0 = (q >> 3)*64, c0 = (q & 7)*64;
            #pragma unroll
            for (int it = 0; it < 16; it++)
                tl[tr + it*4][tc] = W3[(size_t)(i0 + tr + it*4)*512 + c0 + tc];
            __syncthreads();
            #pragma unroll
            for (int it = 0; it < 16; it++) {
                int c = c0 + tr + it*4;
                int i = i0 + tc;
                int byte = c*256 + ((i*2) ^ ((c&15)<<4));
                *(unsigned short*)((char*)W3T + byte) = bf16u(tl[tc][tr + it*4]);
            }
        } else {
            for (int e = t; e < 8192; e += 256) {
                int i = e & 127, j = e >> 7;      // coalesced read over i
                W2T[i*64 + j] = __float2bfloat16(W2[(size_t)j*128 + i]);
            }
        }
        return;
    }

    // ---- FPS path: 256 threads, POINTS IN REGISTERS, (v,i) butterfly,
    //      owner-thread broadcasts center via LDS (2 barriers/step, double-buffered)
    int b = blockIdx.x;
    int t = threadIdx.x;
    __shared__ float redv[2][4];
    __shared__ int   redi[2][4];
    __shared__ float cwr[2][4];
    __shared__ float cbuf[NS*3];

    const float* pb = pos + (size_t)b * NP * 3;
    float rx[8], ry[8], rz[8], dl[8];
    #pragma unroll
    for (int q = 0; q < 8; q++) {
        int n = t + q*256;
        rx[q] = pb[n*3+0]; ry[q] = pb[n*3+1]; rz[q] = pb[n*3+2];
    }

    float cx = pb[0], cy = pb[1], cz = pb[2];     // broadcast (uniform addr)
    if (t == 0) { cbuf[0] = cx; cbuf[1] = cy; cbuf[2] = cz; }

    float bv = -1.0f; int bi = 0;
    #pragma unroll
    for (int q = 0; q < 8; q++) {
        dl[q] = d2s(rx[q],ry[q],rz[q], cx,cy,cz);
        if (dl[q] > bv) { bv = dl[q]; bi = t + q*256; }
    }

    int w = t >> 6;
    for (int s = 1; s < NS; s++) {
        // wave butterfly over (v,i), min-index on equal
        #pragma unroll
        for (int m = 32; m > 0; m >>= 1) {
            float ov = __shfl_xor(bv, m);
            int   oi = __shfl_xor(bi, m);
            if (ov > bv || (ov == bv && oi < bi)) { bv = ov; bi = oi; }
        }
        int s1 = s & 1;
        if ((t & 63) == 0) { redv[s1][w] = bv; redi[s1][w] = bi; }
        __syncthreads();
        float v = redv[s1][0]; int j = redi[s1][0];
        #pragma unroll
        for (int k = 1; k < 4; k++) {
            if (redv[s1][k] > v || (redv[s1][k] == v && redi[s1][k] < j)) { v = redv[s1][k]; j = redi[s1][k]; }
        }
        // owner thread extracts center from its registers (static select) and broadcasts
        if (t == (j & 255)) {
            int qq = j >> 8;
            float ox = rx[0], oy = ry[0], oz = rz[0];
            #pragma unroll
            for (int q = 1; q < 8; q++)
                if (q == qq) { ox = rx[q]; oy = ry[q]; oz = rz[q]; }
            cwr[s1][0] = ox; cwr[s1][1] = oy; cwr[s1][2] = oz;
            cbuf[s*3+0] = ox; cbuf[s*3+1] = oy; cbuf[s*3+2] = oz;
        }
        __syncthreads();
        cx = cwr[s1][0]; cy = cwr[s1][1]; cz = cwr[s1][2];
        // fused update + local argmax (registers only)
        bv = -1.0f; bi = 0;
        #pragma unroll
        for (int q = 0; q < 8; q++) {
            float nd = fminf(dl[q], d2s(rx[q],ry[q],rz[q], cx,cy,cz));
            dl[q] = nd;
            if (nd > bv) { bv = nd; bi = t + q*256; }
        }
    }
    __syncthreads();
    for (int e = t; e < NS*3; e += 256)
        centersWs[(size_t)b*NS*3 + e] = cbuf[e];
}

// ---------------- fused ball query + MLP(3->64->128->512) + masked max, no-h2s ----------------
// LDS map (37392 B):
//   @0     16 KB : layer1 h1s [k][j] swz (k&7)<<4; layer3 bufs for chunks t%4==2 (@0), t%4==3 (@8192)
//   @16384 16 KB : layer3 bufs for chunks t%4==0 (@16384), t%4==1 (@24576); redf[4][512] @16384 after loop
//   @32768 2 KB  : nbL int[4][128]  (scan)  /  relL f32[128][4] (after)
//   @34816 512 B : b2s
//   @35328 2 KB  : b3s
//   @37376 16 B  : cntW4
__global__ __launch_bounds__(256, 4) void ball_mlp_kernel(
    const float* __restrict__ pos,
    const float* __restrict__ W1, const float* __restrict__ b1,
    const float* __restrict__ b2, const float* __restrict__ b3,
    const __hip_bfloat16* __restrict__ W2Tp,
    const __hip_bfloat16* __restrict__ W3Tp,
    const float* __restrict__ centersWs,
    float* __restrict__ out,
    __hip_bfloat16* __restrict__ gAb)
{
    __shared__ char smem[37392];
    char*  h1s  = smem;
    float* relL = (float*)(smem + 32768);
    int*   nbL  = (int*)(smem + 32768);
    float* b2s  = (float*)(smem + 34816);
    float* b3s  = (float*)(smem + 35328);
    int*   cntW4= (int*)(smem + 37376);

    const short* W2T  = (const short*)W2Tp;
    const char*  W3Tb = (const char*)W3Tp;

    int r = blockIdx.x, b = r >> 6, tid = threadIdx.x;
    int l = tid & 63, w = tid >> 6;
    int l31 = l & 31;
    int hsel = l >> 5;
    int jsel8 = hsel * 8;
    int colsel = hsel * 16;

#define STAGE_W3(CH, DST)                                                                              \
    {                                                                                                  \
        const char* _s = W3Tb + (CH)*8192 + w*2048 + l*16;                                             \
        char* _d = (DST) + w*2048;                                                                     \
        __builtin_amdgcn_global_load_lds((const __attribute__((address_space(1))) void*)(_s),          \
                                         (__attribute__((address_space(3))) void*)(_d), 16, 0, 0);     \
        __builtin_amdgcn_global_load_lds((const __attribute__((address_space(1))) void*)(_s + 1024),   \
                                         (__attribute__((address_space(3))) void*)(_d + 1024), 16, 0, 0); \
    }

    // chunk t lives in buf at smem + 8192*((t+2)&3): chunks 0,1 -> dedicated region, stage NOW
    STAGE_W3(0, smem + 16384);
    STAGE_W3(1, smem + 24576);

    float cx = centersWs[r*3+0], cy = centersWs[r*3+1], cz = centersWs[r*3+2];

    // ---- ball query: wave w scans points [w*512, w*512+512), ordered compaction
    const float* pb = pos + (size_t)b * NP * 3;
    {
        int myCnt = 0;
        #pragma unroll
        for (int c = 0; c < 8; c++) {
            int n = w*512 + c*64 + l;
            float x = pb[n*3+0], y = pb[n*3+1], z = pb[n*3+2];
            bool in = d2s(cx,cy,cz, x,y,z) < 0.04f;
            unsigned long long m = __ballot(in);
            int before = __popcll(m & ((1ull << l) - 1ull));
            int p = myCnt + before;
            if (in && p < NK) nbL[w*NK + p] = n;
            myCnt += (int)__popcll(m);
        }
        if (l == 0) cntW4[w] = myCnt;
    }
    // stage b3 -> LDS while scan settles
    b3s[tid] = b3[tid];
    b3s[tid + 256] = b3[tid + 256];
    __syncthreads();

    int c0 = cntW4[0], c1 = cntW4[1], c2 = cntW4[2], c3 = cntW4[3];
    int cnt = c0 + c1 + c2 + c3;
    cnt = cnt > NK ? NK : cnt;

    int nv = 0;
    if (tid < NK) {
        bool valid = tid < cnt;
        int seg = 0, off = 0;
        if (tid >= c0)           { seg = 1; off = c0; }
        if (tid >= c0 + c1)      { seg = 2; off = c0 + c1; }
        if (tid >= c0 + c1 + c2) { seg = 3; off = c0 + c1 + c2; }
        if (valid) nv = nbL[seg*NK + (tid - off)];
        out[XIDX_OFF + r*NK + tid] = valid ? (float)(nv + b*NP) : -1.0f;
        out[YIDX_OFF + r*NK + tid] = valid ? (float)r : -1.0f;
    }
    __syncthreads();          // nbL reads complete before relL overwrite

    if (tid < NK) {
        const float* pp = pb + (size_t)nv*3;
        relL[tid*4+0] = pp[0] - cx;
        relL[tid*4+1] = pp[1] - cy;
        relL[tid*4+2] = pp[2] - cz;
        relL[tid*4+3] = 0.0f;
        b2s[tid] = b2[tid];
    }
    __syncthreads();

    // ---- layer 1 (VALU): h1[k][j] = leaky(rel[k]·W1[:,j] + b1[j])
    {
        int jg = (tid & 15) * 4;
        float4 w0 = *(const float4*)&W1[jg];
        float4 w1 = *(const float4*)&W1[64 + jg];
        float4 w2 = *(const float4*)&W1[128 + jg];
        float4 bb = *(const float4*)&b1[jg];
        #pragma unroll
        for (int e = 0; e < 8; e++) {
            int k = (tid >> 4) + e*16;
            float4 r4 = *(const float4*)&relL[k*4];
            s4 pk;
            pk[0] = (short)bf16u(leaky(bb.x + r4.x*w0.x + r4.y*w1.x + r4.z*w2.x));
            pk[1] = (short)bf16u(leaky(bb.y + r4.x*w0.y + r4.y*w1.y + r4.z*w2.y));
            pk[2] = (short)bf16u(leaky(bb.z + r4.x*w0.z + r4.y*w1.z + r4.z*w2.z));
            pk[3] = (short)bf16u(leaky(bb.w + r4.x*w0.w + r4.y*w1.w + r4.z*w2.w));
            *(s4*)(h1s + k*128 + ((jg*2) ^ ((k&7)<<4))) = pk;
        }
    }
    __syncthreads();

    // ---- layer 2 (MFMA): wave w computes D2[i][k] for ALL i, k = w*32 + l31.
    // C-regs repacked in-register (cvt_pk + permlane32_swap) into layer3 A-frags a3[8].
    short8 a3[8];
    {
        int kcol = w*32 + l31;
        short8 bh[4];
        #pragma unroll
        for (int ks = 0; ks < 4; ks++) {
            int bc = ks*32 + colsel;
            bh[ks] = *(short8*)(h1s + kcol*128 + (bc ^ ((kcol&7)<<4)));
        }
        #pragma unroll
        for (int it = 0; it < 4; it++) {
            short8 aWf[4];
            #pragma unroll
            for (int ks = 0; ks < 4; ks++)
                aWf[ks] = *(const short8*)(W2T + (it*32 + l31)*64 + ks*16 + jsel8);
            f32x16 acc;
            #pragma unroll
            for (int q = 0; q < 16; q++) acc[q] = 0.f;
            #pragma unroll
            for (int ks = 0; ks < 4; ks++)
                acc = __builtin_amdgcn_mfma_f32_32x32x16_bf16(aWf[ks], bh[ks], acc, 0, 0, 0);
            // bias + leaky: acc[reg] holds i = it*32 + 4*hsel + (reg&3) + 8*(reg>>2)
            int ibase = it*32 + 4*hsel;
            #pragma unroll
            for (int g = 0; g < 4; g++) {
                float4 bb = *(const float4*)&b2s[ibase + g*8];
                acc[g*4+0] = leaky(acc[g*4+0] + bb.x);
                acc[g*4+1] = leaky(acc[g*4+1] + bb.y);
                acc[g*4+2] = leaky(acc[g*4+2] + bb.z);
                acc[g*4+3] = leaky(acc[g*4+3] + bb.w);
            }
            // repack: regs hf*8+0..7 -> frag 2it+hf (i = (2it+hf)*16 + jsel8 + 0..7 per lane)
            #pragma unroll
            for (int hf = 0; hf < 2; hf++) {
                unsigned A0 = cvtpk(acc[hf*8+0], acc[hf*8+1]);
                unsigned A1 = cvtpk(acc[hf*8+2], acc[hf*8+3]);
                unsigned B0 = cvtpk(acc[hf*8+4], acc[hf*8+5]);
                unsigned B1 = cvtpk(acc[hf*8+6], acc[hf*8+7]);
                plswap(A0, B0);
                plswap(A1, B1);
                union { unsigned u[4]; short8 s; } f;
                f.u[0] = A0; f.u[1] = A1; f.u[2] = B0; f.u[3] = B1;
                a3[2*it + hf] = f.s;
            }
        }
    }
    __syncthreads();     // all h1s reads done -> h1s region becomes W3 bufs

    // stage chunks 2,3 into h1s region: (2+2)&3=0 -> @0, (3+2)&3=1 -> @8192
    STAGE_W3(2, smem);
    STAGE_W3(3, smem + 8192);

    // ---- layer 3: 16 chunks of 32 cols, 4-buffer pipeline, one barrier/chunk, max in regs
    int kb0 = w*32 + 4*hsel;
    float mred[16];
    #pragma unroll
    for (int t = 0; t < 16; t++) {
        if (t <= 13)      { asm volatile("s_waitcnt vmcnt(4)" ::: "memory"); }
        else if (t == 14) { asm volatile("s_waitcnt vmcnt(2)" ::: "memory"); }
        else              { asm volatile("s_waitcnt vmcnt(0)" ::: "memory"); }
        __builtin_amdgcn_sched_barrier(0);
        __builtin_amdgcn_s_barrier();
        __builtin_amdgcn_sched_barrier(0);

        if (t >= 1 && t + 3 < 16) {
            char* nbuf = smem + 8192*((t+1)&3);     // chunk t+3's buf = (t+5)&3 = (t+1)&3, freed at this barrier
            STAGE_W3(t+3, nbuf);
        }
        __builtin_amdgcn_sched_barrier(0);

        char* buf = smem + 8192*((t+2)&3);
        f32x16 acc;
        #pragma unroll
        for (int q = 0; q < 16; q++) acc[q] = 0.f;
        #pragma unroll
        for (int ks = 0; ks < 8; ks++) {
            int bc = ks*32 + colsel;
            short8 bv = *(short8*)(buf + l31*256 + (bc ^ ((l31&15)<<4)));
            acc = __builtin_amdgcn_mfma_f32_32x32x16_bf16(a3[ks], bv, acc, 0, 0, 0);
        }
        float m = -INFINITY;
        #pragma unroll
        for (int reg = 0; reg < 16; reg++) {
            int kloc = (reg&3) + 8*(reg>>2);
            if (kb0 + kloc < cnt) m = fmaxf(m, acc[reg]);
        }
        m = fmaxf(m, __shfl_xor(m, 32));
        mred[t] = m;
        __builtin_amdgcn_sched_barrier(0);
    }

    // ---- final: dump per-wave partials (bufs for chunks <=13 are dead), reduce, write gAb
    float* redf = (float*)(smem + 16384);
    if (l < 32) {
        #pragma unroll
        for (int t = 0; t < 16; t++)
            redf[w*512 + t*32 + l31] = mred[t];
    }
    __syncthreads();
    #pragma unroll
    for (int e = 0; e < 2; e++) {
        int c = tid + e*256;
        float m = fmaxf(fmaxf(redf[c], redf[512 + c]), fmaxf(redf[1024 + c], redf[1536 + c]));
        gAb[(size_t)r*GA_LD + c] = __float2bfloat16(leaky(m + b3s[c]));
    }
    if (tid < 64) {
        float v = 0.0f;
        if (tid == 0) v = cx; else if (tid == 1) v = cy; else if (tid == 2) v = cz;
        gAb[(size_t)r*GA_LD + 512 + tid] = __float2bfloat16(v);
    }
#undef STAGE_W3
}

// ---------------- FC1 (MFMA): g2b = leaky(gAb[2048,576] @ W4T' + b4), N=512 ----------------
__global__ __launch_bounds__(256) void fc1_kernel(const __hip_bfloat16* __restrict__ gAb,
                                                  const __hip_bfloat16* __restrict__ W4T,
                                                  const float* __restrict__ b4,
                                                  __hip_bfloat16* __restrict__ g2b)
{
    __shared__ char smem[16384];
    char* As = smem;            // [64 rows][64 k] bf16, swz ((row&7)<<4)
    char* Bs = smem + 8192;     // [64 cols][64 k] bf16, swz

    int bx = blockIdx.x & 7;    // N tile (512/64)
    int by = blockIdx.x >> 3;   // M tile (2048/64)
    int tid = threadIdx.x;
    int l = tid & 63, w = tid >> 6;
    int wm = w & 1, wn = w >> 1;
    int colsel = (l >> 5) * 16;

    f32x16 acc;
    #pragma unroll
    for (int q = 0; q < 16; q++) acc[q] = 0.f;

    int ra = wm*32 + (l & 31);
    int rn = wn*32 + (l & 31);

    for (int kb = 0; kb < GA_LD; kb += 64) {
        #pragma unroll
        for (int it = 0; it < 2; it++) {
            int e = it*256 + tid;            // 0..511
            int row = e >> 3, seg = e & 7;
            short8 va = *(const short8*)(gAb + (size_t)(by*64 + row)*GA_LD + kb + seg*8);
            *(short8*)(As + row*128 + ((seg*16) ^ ((row&7)<<4))) = va;
            short8 vb = *(const short8*)(W4T + (size_t)(bx*64 + row)*GA_LD + kb + seg*8);
            *(short8*)(Bs + row*128 + ((seg*16) ^ ((row&7)<<4))) = vb;
        }
        __syncthreads();
        #pragma unroll
        for (int ks = 0; ks < 4; ks++) {
            int bc = ks*32 + colsel;
            short8 av = *(short8*)(As + ra*128 + (bc ^ ((ra&7)<<4)));
            short8 bv = *(short8*)(Bs + rn*128 + (bc ^ ((rn&7)<<4)));
            acc = __builtin_amdgcn_mfma_f32_32x32x16_bf16(av, bv, acc, 0, 0, 0);
        }
        __syncthreads();
    }

    int col = bx*64 + wn*32 + (l & 31);
    float bcol = b4[col];
    int rbase = by*64 + wm*32 + 4*(l>>5);
    #pragma unroll
    for (int reg = 0; reg < 16; reg++) {
        int row = rbase + (reg&3) + 8*(reg>>2);
        g2b[(size_t)row*512 + col] = __float2bfloat16(leaky(acc[reg] + bcol));
    }
}

// ---------------- FC2 (MFMA): out = g2b @ W5T' + b5; mean | std=exp(0.5 lv) ----------------
__global__ __launch_bounds__(256) void fc2_kernel(const __hip_bfloat16* __restrict__ g2b,
                                                  const __hip_bfloat16* __restrict__ W5T,
                                                  const float* __restrict__ b5,
                                                  float* __restrict__ out)
{
    __shared__ char smem[16384];
    char* As = smem;
    char* Bs = smem + 8192;

    int bx = blockIdx.x & 15;   // N tile (1024/64)
    int by = blockIdx.x >> 4;   // M tile (2048/64)
    int tid = threadIdx.x;
    int l = tid & 63, w = tid >> 6;
    int wm = w & 1, wn = w >> 1;
    int colsel = (l >> 5) * 16;

    f32x16 acc;
    #pragma unroll
    for (int q = 0; q < 16; q++) acc[q] = 0.f;

    int ra = wm*32 + (l & 31);
    int rn = wn*32 + (l & 31);

    for (int kb = 0; kb < 512; kb += 64) {
        #pragma unroll
        for (int it = 0; it < 2; it++) {
            int e = it*256 + tid;
            int row = e >> 3, seg = e & 7;
            short8 va = *(const short8*)(g2b + (size_t)(by*64 + row)*512 + kb + seg*8);
            *(short8*)(As + row*128 + ((seg*16) ^ ((row&7)<<4))) = va;
            short8 vb = *(const short8*)(W5T + (size_t)(bx*64 + row)*512 + kb + seg*8);
            *(short8*)(Bs + row*128 + ((seg*16) ^ ((row&7)<<4))) = vb;
        }
        __syncthreads();
        #pragma unroll
        for (int ks = 0; ks < 4; ks++) {
            int bc = ks*32 + colsel;
            short8 av = *(short8*)(As + ra*128 + (bc ^ ((ra&7)<<4)));
            short8 bv = *(short8*)(Bs + rn*128 + (bc ^ ((rn&7)<<4)));
            acc = __builtin_amdgcn_mfma_f32_32x32x16_bf16(av, bv, acc, 0, 0, 0);
        }
        __syncthreads();
    }

    int col = bx*64 + wn*32 + (l & 31);
    float bcol = b5[col];
    int rbase = by*64 + wm*32 + 4*(l>>5);
    #pragma unroll
    for (int reg = 0; reg < 16; reg++) {
        int row = rbase + (reg&3) + 8*(reg>>2);
        float v = acc[reg] + bcol;
        if (col < 512) {
            out[MEAN_OFF + (size_t)row*512 + col] = v;
        } else {
            out[STD_OFF + (size_t)row*512 + (col - 512)] = expf(0.5f*v);
        }
    }
}

extern "C" void kernel_launch(void* const* d_in, const int* in_sizes, int n_in,
                              void* d_out, int out_size, void* d_ws, size_t ws_size,
                              hipStream_t stream) {
    const float* pos = (const float*)d_in[0];
    const float* W1  = (const float*)d_in[2];
    const float* b1  = (const float*)d_in[3];
    const float* W2  = (const float*)d_in[4];
    const float* b2  = (const float*)d_in[5];
    const float* W3  = (const float*)d_in[6];
    const float* b3  = (const float*)d_in[7];
    const float* W4  = (const float*)d_in[8];
    const float* b4  = (const float*)d_in[9];
    const float* W5  = (const float*)d_in[10];
    const float* b5  = (const float*)d_in[11];
    float* out = (float*)d_out;

    char* ws = (char*)d_ws;
    float* centersWs = (float*)(ws);                          // 24576 B
    __hip_bfloat16* gAb = (__hip_bfloat16*)(ws + 1081344);    // 2048*576*2 = 2359296
    __hip_bfloat16* g2b = (__hip_bfloat16*)(ws + 3440640);    // 2048*512*2 = 2097152
    __hip_bfloat16* W2T = (__hip_bfloat16*)(ws + 5537792);    // 16 KB
    __hip_bfloat16* W3T = (__hip_bfloat16*)(ws + 5554176);    // 128 KB
    __hip_bfloat16* W4T = (__hip_bfloat16*)(ws + 5685248);    // 576 KB
    __hip_bfloat16* W5T = (__hip_bfloat16*)(ws + 6275072);    // 1 MB -> ends 7323648

    hipLaunchKernelGGL(fps_prep_kernel, dim3(NB + 217), dim3(256), 0, stream,
                       pos, centersWs, W2, W3, W4, W5, W2T, W3T, W4T, W5T);
    hipLaunchKernelGGL(ball_mlp_kernel, dim3(NB*NS), dim3(256), 0, stream,
                       pos, W1,b1, b2,b3, W2T, W3T, centersWs, out, gAb);
    hipLaunchKernelGGL(fc1_kernel, dim3(256), dim3(256), 0, stream, gAb, W4T, b4, g2b);
    hipLaunchKernelGGL(fc2_kernel, dim3(512), dim3(256), 0, stream, g2b, W5T, b5, out);
}

// Round 13
// 143.215 us; speedup vs baseline: 1.0935x; 1.0229x over previous
//
#include <hip/hip_runtime.h>
#include <hip/hip_bf16.h>

#define NB 32
#define NP 2048
#define NS 64
#define NK 128

// d_out layout (FLOAT32 elements)
#define MEAN_OFF 0
#define STD_OFF  1048576
#define XIDX_OFF 2097152
#define YIDX_OFF 2359296

#define GA_LD 576   // gA bf16 leading dim (515 padded)

typedef __attribute__((ext_vector_type(4)))  short s4;
typedef __attribute__((ext_vector_type(8)))  short short8;
typedef __attribute__((ext_vector_type(16))) float f32x16;

static __device__ __forceinline__ float leaky(float x){ return x >= 0.0f ? x : 0.2f * x; }

static __device__ __forceinline__ unsigned short bf16u(float v){
    __hip_bfloat16 h = __float2bfloat16(v);
    return *(unsigned short*)&h;
}

static __device__ __forceinline__ unsigned cvtpk(float a, float b){
    unsigned d;
    asm("v_cvt_pk_bf16_f32 %0, %1, %2" : "=v"(d) : "v"(a), "v"(b));
    return d;
}
static __device__ __forceinline__ void plswap(unsigned &a, unsigned &b){
    asm volatile("v_permlane32_swap_b32 %0, %1" : "+v"(a), "+v"(b));
}

// DPP row_ror reduce step over (value, index): max-value, min-index on ties.
// row_ror rotates within rows of 16 lanes; 1,2,4,8 give a full 16-lane reduce.
template<int CTRL>
static __device__ __forceinline__ void dpp_step(float &bv, int &bi){
    int ovi = __builtin_amdgcn_update_dpp(0, __float_as_int(bv), CTRL, 0xF, 0xF, true);
    int oi  = __builtin_amdgcn_update_dpp(0, bi, CTRL, 0xF, 0xF, true);
    float ov = __int_as_float(ovi);
    if (ov > bv || (ov == bv && oi < bi)) { bv = ov; bi = oi; }
}

// strict IEEE fp32, no contraction — matches numpy/jax op order
static __device__ __forceinline__ float d2s(float ax,float ay,float az,float bx,float by,float bz){
    float dx = __fsub_rn(ax,bx), dy = __fsub_rn(ay,by), dz = __fsub_rn(az,bz);
    return __fadd_rn(__fadd_rn(__fmul_rn(dx,dx),__fmul_rn(dy,dy)),__fmul_rn(dz,dz));
}

// ---------------- FPS (blocks 0..31, single wave) + coalesced tiled weight prep ----------------
__global__ __launch_bounds__(256) void fps_prep_kernel(const float* __restrict__ pos,
                                                       float* __restrict__ centersWs,
                                                       const float* __restrict__ W2,
                                                       const float* __restrict__ W3,
                                                       const float* __restrict__ W4,
                                                       const float* __restrict__ W5,
                                                       __hip_bfloat16* __restrict__ W2T,
                                                       __hip_bfloat16* __restrict__ W3T,
                                                       __hip_bfloat16* __restrict__ W4T,
                                                       __hip_bfloat16* __restrict__ W5T)
{
    if (blockIdx.x >= NB) {
        __shared__ float tl[64][65];
        int tb = blockIdx.x - NB;       // 0..216
        int t = threadIdx.x;
        int tr = t >> 6;                // 0..3
        int tc = t & 63;
        if (tb < 72) {
            int kt = tb >> 3, nt = tb & 7;
            int k0 = kt*64, n0 = nt*64;
            #pragma unroll
            for (int it = 0; it < 16; it++) {
                int k = k0 + tr + it*4;
                tl[tr + it*4][tc] = (k < 515) ? W4[(size_t)k*512 + n0 + tc] : 0.0f;
            }
            __syncthreads();
            #pragma unroll
            for (int it = 0; it < 16; it++) {
                int nl = tr + it*4;
                W4T[(size_t)(n0 + nl)*GA_LD + k0 + tc] = __float2bfloat16(tl[tc][nl]);
            }
        } else if (tb < 200) {
            int q = tb - 72;
            int kt = q >> 4, nt = q & 15;
            int k0 = kt*64, n0 = nt*64;
            #pragma unroll
            for (int it = 0; it < 16; it++)
                tl[tr + it*4][tc] = W5[(size_t)(k0 + tr + it*4)*1024 + n0 + tc];
            __syncthreads();
            #pragma unroll
            for (int it = 0; it < 16; it++) {
                int nl = tr + it*4;
                W5T[(size_t)(n0 + nl)*512 + k0 + tc] = __float2bfloat16(tl[tc][nl]);
            }
        } else if (tb < 216) {
            int q = tb - 200;
            int i0 = (q >> 3)*64, c0 = (q & 7)*64;
            #pragma unroll
            for (int it = 0; it < 16; it++)
                tl[tr + it*4][tc] = W3[(size_t)(i0 + tr + it*4)*512 + c0 + tc];
            __syncthreads();
            #pragma unroll
            for (int it = 0; it < 16; it++) {
                int c = c0 + tr + it*4;
                int i = i0 + tc;
                int byte = c*256 + ((i*2) ^ ((c&15)<<4));
                *(unsigned short*)((char*)W3T + byte) = bf16u(tl[tc][tr + it*4]);
            }
        } else {
            for (int e = t; e < 8192; e += 256) {
                int i = e & 127, j = e >> 7;      // coalesced read over i
                W2T[i*64 + j] = __float2bfloat16(W2[(size_t)j*128 + i]);
            }
        }
        return;
    }

    // ---- FPS path: SINGLE WAVE, 32 points/lane in registers, DPP rotation reduce,
    //      center broadcast via LDS point cache (uniform-address read), no barriers.
    __shared__ float pxL[NP], pyL[NP], pzL[NP];
    __shared__ float cbuf[NS*3];

    int t = threadIdx.x;
    if (t >= 64) return;
    int b = blockIdx.x;

    const float* pb = pos + (size_t)b * NP * 3;
    float rx[32], ry[32], rz[32], dl[32];
    #pragma unroll
    for (int q = 0; q < 32; q++) {
        int n = t + q*64;
        float x = pb[n*3+0], y = pb[n*3+1], z = pb[n*3+2];
        rx[q] = x; ry[q] = y; rz[q] = z;
        pxL[n] = x; pyL[n] = y; pzL[n] = z;
    }

    float cx = pb[0], cy = pb[1], cz = pb[2];     // broadcast (uniform addr)
    if (t == 0) { cbuf[0] = cx; cbuf[1] = cy; cbuf[2] = cz; }

    float bv = -1.0f; int bi = 0;
    #pragma unroll
    for (int q = 0; q < 32; q++) {
        dl[q] = d2s(rx[q],ry[q],rz[q], cx,cy,cz);
        if (dl[q] > bv) { bv = dl[q]; bi = t + q*64; }
    }

    for (int s = 1; s < NS; s++) {
        // 64-lane argmax reduce: 4 DPP rotations (16-lane rows) + 2 shuffles
        dpp_step<0x121>(bv, bi);   // row_ror:1
        dpp_step<0x122>(bv, bi);   // row_ror:2
        dpp_step<0x124>(bv, bi);   // row_ror:4
        dpp_step<0x128>(bv, bi);   // row_ror:8
        {
            float ov = __shfl_xor(bv, 16);
            int   oi = __shfl_xor(bi, 16);
            if (ov > bv || (ov == bv && oi < bi)) { bv = ov; bi = oi; }
        }
        {
            float ov = __shfl_xor(bv, 32);
            int   oi = __shfl_xor(bi, 32);
            if (ov > bv || (ov == bv && oi < bi)) { bv = ov; bi = oi; }
        }
        int j = bi;                      // identical on all lanes
        cx = pxL[j]; cy = pyL[j]; cz = pzL[j];   // LDS broadcast
        if (t == 0) { cbuf[s*3+0] = cx; cbuf[s*3+1] = cy; cbuf[s*3+2] = cz; }
        // fused distance update + local argmax (registers only)
        bv = -1.0f; bi = 0;
        #pragma unroll
        for (int q = 0; q < 32; q++) {
            float nd = fminf(dl[q], d2s(rx[q],ry[q],rz[q], cx,cy,cz));
            dl[q] = nd;
            if (nd > bv) { bv = nd; bi = t + q*64; }
        }
    }
    #pragma unroll
    for (int e = 0; e < 3; e++)
        centersWs[(size_t)b*NS*3 + t + e*64] = cbuf[t + e*64];
}

// ---------------- fused ball query + MLP(3->64->128->512) + masked max, no-h2s ----------------
// LDS map (37392 B):
//   @0     16 KB : layer1 h1s [k][j] swz (k&7)<<4; layer3 bufs for chunks t%4==2 (@0), t%4==3 (@8192)
//   @16384 16 KB : layer3 bufs for chunks t%4==0 (@16384), t%4==1 (@24576); redf[4][512] @16384 after loop
//   @32768 2 KB  : nbL int[4][128]  (scan)  /  relL f32[128][4] (after)
//   @34816 512 B : b2s
//   @35328 2 KB  : b3s
//   @37376 16 B  : cntW4
__global__ __launch_bounds__(256, 4) void ball_mlp_kernel(
    const float* __restrict__ pos,
    const float* __restrict__ W1, const float* __restrict__ b1,
    const float* __restrict__ b2, const float* __restrict__ b3,
    const __hip_bfloat16* __restrict__ W2Tp,
    const __hip_bfloat16* __restrict__ W3Tp,
    const float* __restrict__ centersWs,
    float* __restrict__ out,
    __hip_bfloat16* __restrict__ gAb)
{
    __shared__ char smem[37392];
    char*  h1s  = smem;
    float* relL = (float*)(smem + 32768);
    int*   nbL  = (int*)(smem + 32768);
    float* b2s  = (float*)(smem + 34816);
    float* b3s  = (float*)(smem + 35328);
    int*   cntW4= (int*)(smem + 37376);

    const short* W2T  = (const short*)W2Tp;
    const char*  W3Tb = (const char*)W3Tp;

    int r = blockIdx.x, b = r >> 6, tid = threadIdx.x;
    int l = tid & 63, w = tid >> 6;
    int l31 = l & 31;
    int hsel = l >> 5;
    int jsel8 = hsel * 8;
    int colsel = hsel * 16;

#define STAGE_W3(CH, DST)                                                                              \
    {                                                                                                  \
        const char* _s = W3Tb + (CH)*8192 + w*2048 + l*16;                                             \
        char* _d = (DST) + w*2048;                                                                     \
        __builtin_amdgcn_global_load_lds((const __attribute__((address_space(1))) void*)(_s),          \
                                         (__attribute__((address_space(3))) void*)(_d), 16, 0, 0);     \
        __builtin_amdgcn_global_load_lds((const __attribute__((address_space(1))) void*)(_s + 1024),   \
                                         (__attribute__((address_space(3))) void*)(_d + 1024), 16, 0, 0); \
    }

    // chunk t lives in buf at smem + 8192*((t+2)&3): chunks 0,1 -> dedicated region, stage NOW
    STAGE_W3(0, smem + 16384);
    STAGE_W3(1, smem + 24576);

    float cx = centersWs[r*3+0], cy = centersWs[r*3+1], cz = centersWs[r*3+2];

    // ---- ball query: wave w scans points [w*512, w*512+512), ordered compaction
    const float* pb = pos + (size_t)b * NP * 3;
    {
        int myCnt = 0;
        #pragma unroll
        for (int c = 0; c < 8; c++) {
            int n = w*512 + c*64 + l;
            float x = pb[n*3+0], y = pb[n*3+1], z = pb[n*3+2];
            bool in = d2s(cx,cy,cz, x,y,z) < 0.04f;
            unsigned long long m = __ballot(in);
            int before = __popcll(m & ((1ull << l) - 1ull));
            int p = myCnt + before;
            if (in && p < NK) nbL[w*NK + p] = n;
            myCnt += (int)__popcll(m);
        }
        if (l == 0) cntW4[w] = myCnt;
    }
    // stage b3 -> LDS while scan settles
    b3s[tid] = b3[tid];
    b3s[tid + 256] = b3[tid + 256];
    __syncthreads();

    int c0 = cntW4[0], c1 = cntW4[1], c2 = cntW4[2], c3 = cntW4[3];
    int cnt = c0 + c1 + c2 + c3;
    cnt = cnt > NK ? NK : cnt;

    int nv = 0;
    if (tid < NK) {
        bool valid = tid < cnt;
        int seg = 0, off = 0;
        if (tid >= c0)           { seg = 1; off = c0; }
        if (tid >= c0 + c1)      { seg = 2; off = c0 + c1; }
        if (tid >= c0 + c1 + c2) { seg = 3; off = c0 + c1 + c2; }
        if (valid) nv = nbL[seg*NK + (tid - off)];
        out[XIDX_OFF + r*NK + tid] = valid ? (float)(nv + b*NP) : -1.0f;
        out[YIDX_OFF + r*NK + tid] = valid ? (float)r : -1.0f;
    }
    __syncthreads();          // nbL reads complete before relL overwrite

    if (tid < NK) {
        const float* pp = pb + (size_t)nv*3;
        relL[tid*4+0] = pp[0] - cx;
        relL[tid*4+1] = pp[1] - cy;
        relL[tid*4+2] = pp[2] - cz;
        relL[tid*4+3] = 0.0f;
        b2s[tid] = b2[tid];
    }
    __syncthreads();

    // ---- layer 1 (VALU): h1[k][j] = leaky(rel[k]·W1[:,j] + b1[j])
    {
        int jg = (tid & 15) * 4;
        float4 w0 = *(const float4*)&W1[jg];
        float4 w1 = *(const float4*)&W1[64 + jg];
        float4 w2 = *(const float4*)&W1[128 + jg];
        float4 bb = *(const float4*)&b1[jg];
        #pragma unroll
        for (int e = 0; e < 8; e++) {
            int k = (tid >> 4) + e*16;
            float4 r4 = *(const float4*)&relL[k*4];
            s4 pk;
            pk[0] = (short)bf16u(leaky(bb.x + r4.x*w0.x + r4.y*w1.x + r4.z*w2.x));
            pk[1] = (short)bf16u(leaky(bb.y + r4.x*w0.y + r4.y*w1.y + r4.z*w2.y));
            pk[2] = (short)bf16u(leaky(bb.z + r4.x*w0.z + r4.y*w1.z + r4.z*w2.z));
            pk[3] = (short)bf16u(leaky(bb.w + r4.x*w0.w + r4.y*w1.w + r4.z*w2.w));
            *(s4*)(h1s + k*128 + ((jg*2) ^ ((k&7)<<4))) = pk;
        }
    }
    __syncthreads();

    // ---- layer 2 (MFMA): wave w computes D2[i][k] for ALL i, k = w*32 + l31.
    // C-regs repacked in-register (cvt_pk + permlane32_swap) into layer3 A-frags a3[8].
    short8 a3[8];
    {
        int kcol = w*32 + l31;
        short8 bh[4];
        #pragma unroll
        for (int ks = 0; ks < 4; ks++) {
            int bc = ks*32 + colsel;
            bh[ks] = *(short8*)(h1s + kcol*128 + (bc ^ ((kcol&7)<<4)));
        }
        #pragma unroll
        for (int it = 0; it < 4; it++) {
            short8 aWf[4];
            #pragma unroll
            for (int ks = 0; ks < 4; ks++)
                aWf[ks] = *(const short8*)(W2T + (it*32 + l31)*64 + ks*16 + jsel8);
            f32x16 acc;
            #pragma unroll
            for (int q = 0; q < 16; q++) acc[q] = 0.f;
            #pragma unroll
            for (int ks = 0; ks < 4; ks++)
                acc = __builtin_amdgcn_mfma_f32_32x32x16_bf16(aWf[ks], bh[ks], acc, 0, 0, 0);
            // bias + leaky: acc[reg] holds i = it*32 + 4*hsel + (reg&3) + 8*(reg>>2)
            int ibase = it*32 + 4*hsel;
            #pragma unroll
            for (int g = 0; g < 4; g++) {
                float4 bb = *(const float4*)&b2s[ibase + g*8];
                acc[g*4+0] = leaky(acc[g*4+0] + bb.x);
                acc[g*4+1] = leaky(acc[g*4+1] + bb.y);
                acc[g*4+2] = leaky(acc[g*4+2] + bb.z);
                acc[g*4+3] = leaky(acc[g*4+3] + bb.w);
            }
            // repack: regs hf*8+0..7 -> frag 2it+hf (i = (2it+hf)*16 + jsel8 + 0..7 per lane)
            #pragma unroll
            for (int hf = 0; hf < 2; hf++) {
                unsigned A0 = cvtpk(acc[hf*8+0], acc[hf*8+1]);
                unsigned A1 = cvtpk(acc[hf*8+2], acc[hf*8+3]);
                unsigned B0 = cvtpk(acc[hf*8+4], acc[hf*8+5]);
                unsigned B1 = cvtpk(acc[hf*8+6], acc[hf*8+7]);
                plswap(A0, B0);
                plswap(A1, B1);
                union { unsigned u[4]; short8 s; } f;
                f.u[0] = A0; f.u[1] = A1; f.u[2] = B0; f.u[3] = B1;
                a3[2*it + hf] = f.s;
            }
        }
    }
    __syncthreads();     // all h1s reads done -> h1s region becomes W3 bufs

    // stage chunks 2,3 into h1s region: (2+2)&3=0 -> @0, (3+2)&3=1 -> @8192
    STAGE_W3(2, smem);
    STAGE_W3(3, smem + 8192);

    // ---- layer 3: 16 chunks of 32 cols, 4-buffer pipeline, one barrier/chunk, max in regs
    int kb0 = w*32 + 4*hsel;
    float mred[16];
    #pragma unroll
    for (int t = 0; t < 16; t++) {
        if (t <= 13)      { asm volatile("s_waitcnt vmcnt(4)" ::: "memory"); }
        else if (t == 14) { asm volatile("s_waitcnt vmcnt(2)" ::: "memory"); }
        else              { asm volatile("s_waitcnt vmcnt(0)" ::: "memory"); }
        __builtin_amdgcn_sched_barrier(0);
        __builtin_amdgcn_s_barrier();
        __builtin_amdgcn_sched_barrier(0);

        if (t >= 1 && t + 3 < 16) {
            char* nbuf = smem + 8192*((t+1)&3);     // chunk t+3's buf = (t+5)&3 = (t+1)&3, freed at this barrier
            STAGE_W3(t+3, nbuf);
        }
        __builtin_amdgcn_sched_barrier(0);

        char* buf = smem + 8192*((t+2)&3);
        f32x16 acc;
        #pragma unroll
        for (int q = 0; q < 16; q++) acc[q] = 0.f;
        #pragma unroll
        for (int ks = 0; ks < 8; ks++) {
            int bc = ks*32 + colsel;
            short8 bv = *(short8*)(buf + l31*256 + (bc ^ ((l31&15)<<4)));
            acc = __builtin_amdgcn_mfma_f32_32x32x16_bf16(a3[ks], bv, acc, 0, 0, 0);
        }
        float m = -INFINITY;
        #pragma unroll
        for (int reg = 0; reg < 16; reg++) {
            int kloc = (reg&3) + 8*(reg>>2);
            if (kb0 + kloc < cnt) m = fmaxf(m, acc[reg]);
        }
        m = fmaxf(m, __shfl_xor(m, 32));
        mred[t] = m;
        __builtin_amdgcn_sched_barrier(0);
    }

    // ---- final: dump per-wave partials (bufs for chunks <=13 are dead), reduce, write gAb
    float* redf = (float*)(smem + 16384);
    if (l < 32) {
        #pragma unroll
        for (int t = 0; t < 16; t++)
            redf[w*512 + t*32 + l31] = mred[t];
    }
    __syncthreads();
    #pragma unroll
    for (int e = 0; e < 2; e++) {
        int c = tid + e*256;
        float m = fmaxf(fmaxf(redf[c], redf[512 + c]), fmaxf(redf[1024 + c], redf[1536 + c]));
        gAb[(size_t)r*GA_LD + c] = __float2bfloat16(leaky(m + b3s[c]));
    }
    if (tid < 64) {
        float v = 0.0f;
        if (tid == 0) v = cx; else if (tid == 1) v = cy; else if (tid == 2) v = cz;
        gAb[(size_t)r*GA_LD + 512 + tid] = __float2bfloat16(v);
    }
#undef STAGE_W3
}

// ---------------- FC1 (MFMA): g2b = leaky(gAb[2048,576] @ W4T' + b4), N=512 ----------------
__global__ __launch_bounds__(256) void fc1_kernel(const __hip_bfloat16* __restrict__ gAb,
                                                  const __hip_bfloat16* __restrict__ W4T,
                                                  const float* __restrict__ b4,
                                                  __hip_bfloat16* __restrict__ g2b)
{
    __shared__ char smem[16384];
    char* As = smem;            // [64 rows][64 k] bf16, swz ((row&7)<<4)
    char* Bs = smem + 8192;     // [64 cols][64 k] bf16, swz

    int bx = blockIdx.x & 7;    // N tile (512/64)
    int by = blockIdx.x >> 3;   // M tile (2048/64)
    int tid = threadIdx.x;
    int l = tid & 63, w = tid >> 6;
    int wm = w & 1, wn = w >> 1;
    int colsel = (l >> 5) * 16;

    f32x16 acc;
    #pragma unroll
    for (int q = 0; q < 16; q++) acc[q] = 0.f;

    int ra = wm*32 + (l & 31);
    int rn = wn*32 + (l & 31);

    for (int kb = 0; kb < GA_LD; kb += 64) {
        #pragma unroll
        for (int it = 0; it < 2; it++) {
            int e = it*256 + tid;            // 0..511
            int row = e >> 3, seg = e & 7;
            short8 va = *(const short8*)(gAb + (size_t)(by*64 + row)*GA_LD + kb + seg*8);
            *(short8*)(As + row*128 + ((seg*16) ^ ((row&7)<<4))) = va;
            short8 vb = *(const short8*)(W4T + (size_t)(bx*64 + row)*GA_LD + kb + seg*8);
            *(short8*)(Bs + row*128 + ((seg*16) ^ ((row&7)<<4))) = vb;
        }
        __syncthreads();
        #pragma unroll
        for (int ks = 0; ks < 4; ks++) {
            int bc = ks*32 + colsel;
            short8 av = *(short8*)(As + ra*128 + (bc ^ ((ra&7)<<4)));
            short8 bv = *(short8*)(Bs + rn*128 + (bc ^ ((rn&7)<<4)));
            acc = __builtin_amdgcn_mfma_f32_32x32x16_bf16(av, bv, acc, 0, 0, 0);
        }
        __syncthreads();
    }

    int col = bx*64 + wn*32 + (l & 31);
    float bcol = b4[col];
    int rbase = by*64 + wm*32 + 4*(l>>5);
    #pragma unroll
    for (int reg = 0; reg < 16; reg++) {
        int row = rbase + (reg&3) + 8*(reg>>2);
        g2b[(size_t)row*512 + col] = __float2bfloat16(leaky(acc[reg] + bcol));
    }
}

// ---------------- FC2 (MFMA): out = g2b @ W5T' + b5; mean | std=exp(0.5 lv) ----------------
__global__ __launch_bounds__(256) void fc2_kernel(const __hip_bfloat16* __restrict__ g2b,
                                                  const __hip_bfloat16* __restrict__ W5T,
                                                  const float* __restrict__ b5,
                                                  float* __restrict__ out)
{
    __shared__ char smem[16384];
    char* As = smem;
    char* Bs = smem + 8192;

    int bx = blockIdx.x & 15;   // N tile (1024/64)
    int by = blockIdx.x >> 4;   // M tile (2048/64)
    int tid = threadIdx.x;
    int l = tid & 63, w = tid >> 6;
    int wm = w & 1, wn = w >> 1;
    int colsel = (l >> 5) * 16;

    f32x16 acc;
    #pragma unroll
    for (int q = 0; q < 16; q++) acc[q] = 0.f;

    int ra = wm*32 + (l & 31);
    int rn = wn*32 + (l & 31);

    for (int kb = 0; kb < 512; kb += 64) {
        #pragma unroll
        for (int it = 0; it < 2; it++) {
            int e = it*256 + tid;
            int row = e >> 3, seg = e & 7;
            short8 va = *(const short8*)(g2b + (size_t)(by*64 + row)*512 + kb + seg*8);
            *(short8*)(As + row*128 + ((seg*16) ^ ((row&7)<<4))) = va;
            short8 vb = *(const short8*)(W5T + (size_t)(bx*64 + row)*512 + kb + seg*8);
            *(short8*)(Bs + row*128 + ((seg*16) ^ ((row&7)<<4))) = vb;
        }
        __syncthreads();
        #pragma unroll
        for (int ks = 0; ks < 4; ks++) {
            int bc = ks*32 + colsel;
            short8 av = *(short8*)(As + ra*128 + (bc ^ ((ra&7)<<4)));
            short8 bv = *(short8*)(Bs + rn*128 + (bc ^ ((rn&7)<<4)));
            acc = __builtin_amdgcn_mfma_f32_32x32x16_bf16(av, bv, acc, 0, 0, 0);
        }
        __syncthreads();
    }

    int col = bx*64 + wn*32 + (l & 31);
    float bcol = b5[col];
    int rbase = by*64 + wm*32 + 4*(l>>5);
    #pragma unroll
    for (int reg = 0; reg < 16; reg++) {
        int row = rbase + (reg&3) + 8*(reg>>2);
        float v = acc[reg] + bcol;
        if (col < 512) {
            out[MEAN_OFF + (size_t)row*512 + col] = v;
        } else {
            out[STD_OFF + (size_t)row*512 + (col - 512)] = expf(0.5f*v);
        }
    }
}

extern "C" void kernel_launch(void* const* d_in, const int* in_sizes, int n_in,
                              void* d_out, int out_size, void* d_ws, size_t ws_size,
                              hipStream_t stream) {
    const float* pos = (const float*)d_in[0];
    const float* W1  = (const float*)d_in[2];
    const float* b1  = (const float*)d_in[3];
    const float* W2  = (const float*)d_in[4];
    const float* b2  = (const float*)d_in[5];
    const float* W3  = (const float*)d_in[6];
    const float* b3  = (const float*)d_in[7];
    const float* W4  = (const float*)d_in[8];
    const float* b4  = (const float*)d_in[9];
    const float* W5  = (const float*)d_in[10];
    const float* b5  = (const float*)d_in[11];
    float* out = (float*)d_out;

    char* ws = (char*)d_ws;
    float* centersWs = (float*)(ws);                          // 24576 B
    __hip_bfloat16* gAb = (__hip_bfloat16*)(ws + 1081344);    // 2048*576*2 = 2359296
    __hip_bfloat16* g2b = (__hip_bfloat16*)(ws + 3440640);    // 2048*512*2 = 2097152
    __hip_bfloat16* W2T = (__hip_bfloat16*)(ws + 5537792);    // 16 KB
    __hip_bfloat16* W3T = (__hip_bfloat16*)(ws + 5554176);    // 128 KB
    __hip_bfloat16* W4T = (__hip_bfloat16*)(ws + 5685248);    // 576 KB
    __hip_bfloat16* W5T = (__hip_bfloat16*)(ws + 6275072);    // 1 MB -> ends 7323648

    hipLaunchKernelGGL(fps_prep_kernel, dim3(NB + 217), dim3(256), 0, stream,
                       pos, centersWs, W2, W3, W4, W5, W2T, W3T, W4T, W5T);
    hipLaunchKernelGGL(ball_mlp_kernel, dim3(NB*NS), dim3(256), 0, stream,
                       pos, W1,b1, b2,b3, W2T, W3T, centersWs, out, gAb);
    hipLaunchKernelGGL(fc1_kernel, dim3(256), dim3(256), 0, stream, gAb, W4T, b4, g2b);
    hipLaunchKernelGGL(fc2_kernel, dim3(512), dim3(256), 0, stream, g2b, W5T, b5, out);
}

// Round 14
// 140.696 us; speedup vs baseline: 1.1130x; 1.0179x over previous
//
#include <hip/hip_runtime.h>
#include <hip/hip_bf16.h>

#define NB 32
#define NP 2048
#define NS 64
#define NK 128

// d_out layout (FLOAT32 elements)
#define MEAN_OFF 0
#define STD_OFF  1048576
#define XIDX_OFF 2097152
#define YIDX_OFF 2359296

#define GA_LD 576   // gA bf16 leading dim (515 padded)

typedef __attribute__((ext_vector_type(4)))  short s4;
typedef __attribute__((ext_vector_type(8)))  short short8;
typedef __attribute__((ext_vector_type(16))) float f32x16;

static __device__ __forceinline__ float leaky(float x){ return x >= 0.0f ? x : 0.2f * x; }

static __device__ __forceinline__ unsigned short bf16u(float v){
    __hip_bfloat16 h = __float2bfloat16(v);
    return *(unsigned short*)&h;
}

static __device__ __forceinline__ unsigned cvtpk(float a, float b){
    unsigned d;
    asm("v_cvt_pk_bf16_f32 %0, %1, %2" : "=v"(d) : "v"(a), "v"(b));
    return d;
}
static __device__ __forceinline__ void plswap(unsigned &a, unsigned &b){
    asm volatile("v_permlane32_swap_b32 %0, %1" : "+v"(a), "+v"(b));
}

// DPP row_ror reduce step over (value, index): max-value, min-index on ties.
template<int CTRL>
static __device__ __forceinline__ void dpp_step(float &bv, int &bi){
    int ovi = __builtin_amdgcn_update_dpp(0, __float_as_int(bv), CTRL, 0xF, 0xF, true);
    int oi  = __builtin_amdgcn_update_dpp(0, bi, CTRL, 0xF, 0xF, true);
    float ov = __int_as_float(ovi);
    if (ov > bv || (ov == bv && oi < bi)) { bv = ov; bi = oi; }
}

// strict IEEE fp32, no contraction — matches numpy/jax op order
static __device__ __forceinline__ float d2s(float ax,float ay,float az,float bx,float by,float bz){
    float dx = __fsub_rn(ax,bx), dy = __fsub_rn(ay,by), dz = __fsub_rn(az,bz);
    return __fadd_rn(__fadd_rn(__fmul_rn(dx,dx),__fmul_rn(dy,dy)),__fmul_rn(dz,dz));
}

// ---------------- FPS (blocks 0..31, single wave, LDS float4 points) + tiled prep ----------------
__global__ __launch_bounds__(256) void fps_prep_kernel(const float* __restrict__ pos,
                                                       float* __restrict__ centersWs,
                                                       const float* __restrict__ W2,
                                                       const float* __restrict__ W3,
                                                       const float* __restrict__ W4,
                                                       const float* __restrict__ W5,
                                                       __hip_bfloat16* __restrict__ W2T,
                                                       __hip_bfloat16* __restrict__ W3T,
                                                       __hip_bfloat16* __restrict__ W4T,
                                                       __hip_bfloat16* __restrict__ W5T)
{
    if (blockIdx.x >= NB) {
        __shared__ float tl[64][65];
        int tb = blockIdx.x - NB;       // 0..216
        int t = threadIdx.x;
        int tr = t >> 6;                // 0..3
        int tc = t & 63;
        if (tb < 72) {
            int kt = tb >> 3, nt = tb & 7;
            int k0 = kt*64, n0 = nt*64;
            #pragma unroll
            for (int it = 0; it < 16; it++) {
                int k = k0 + tr + it*4;
                tl[tr + it*4][tc] = (k < 515) ? W4[(size_t)k*512 + n0 + tc] : 0.0f;
            }
            __syncthreads();
            #pragma unroll
            for (int it = 0; it < 16; it++) {
                int nl = tr + it*4;
                W4T[(size_t)(n0 + nl)*GA_LD + k0 + tc] = __float2bfloat16(tl[tc][nl]);
            }
        } else if (tb < 200) {
            int q = tb - 72;
            int kt = q >> 4, nt = q & 15;
            int k0 = kt*64, n0 = nt*64;
            #pragma unroll
            for (int it = 0; it < 16; it++)
                tl[tr + it*4][tc] = W5[(size_t)(k0 + tr + it*4)*1024 + n0 + tc];
            __syncthreads();
            #pragma unroll
            for (int it = 0; it < 16; it++) {
                int nl = tr + it*4;
                W5T[(size_t)(n0 + nl)*512 + k0 + tc] = __float2bfloat16(tl[tc][nl]);
            }
        } else if (tb < 216) {
            int q = tb - 200;
            int i0 = (q >> 3)*64, c0 = (q & 7)*64;
            #pragma unroll
            for (int it = 0; it < 16; it++)
                tl[tr + it*4][tc] = W3[(size_t)(i0 + tr + it*4)*512 + c0 + tc];
            __syncthreads();
            #pragma unroll
            for (int it = 0; it < 16; it++) {
                int c = c0 + tr + it*4;
                int i = i0 + tc;
                int byte = c*256 + ((i*2) ^ ((c&15)<<4));
                *(unsigned short*)((char*)W3T + byte) = bf16u(tl[tc][tr + it*4]);
            }
        } else {
            for (int e = t; e < 8192; e += 256) {
                int i = e & 127, j = e >> 7;      // coalesced read over i
                W2T[i*64 + j] = __float2bfloat16(W2[(size_t)j*128 + i]);
            }
        }
        return;
    }

    // ---- FPS: SINGLE WAVE; dl[32] in regs (32 VGPR, no spill);
    //      points packed float4 in LDS, update reads ds_read_b128; DPP+shfl reduce.
    __shared__ float4 ptsL[NP];          // 32 KB
    __shared__ float cbuf[NS*3];

    int t = threadIdx.x;
    if (t >= 64) return;
    int b = blockIdx.x;

    const float* pb = pos + (size_t)b * NP * 3;
    float cx = pb[0], cy = pb[1], cz = pb[2];     // uniform-address broadcast
    if (t == 0) { cbuf[0] = cx; cbuf[1] = cy; cbuf[2] = cz; }

    float dl[32];
    float bv = -1.0f; int bi = 0;
    #pragma unroll
    for (int q = 0; q < 32; q++) {
        int n = t + q*64;
        float x = pb[n*3+0], y = pb[n*3+1], z = pb[n*3+2];
        ptsL[n] = make_float4(x, y, z, 0.0f);
        dl[q] = d2s(x,y,z, cx,cy,cz);
        if (dl[q] > bv) { bv = dl[q]; bi = n; }
    }

    for (int s = 1; s < NS; s++) {
        // 64-lane argmax reduce: 4 DPP rotations (16-lane rows) + 2 shuffles
        dpp_step<0x121>(bv, bi);   // row_ror:1
        dpp_step<0x122>(bv, bi);   // row_ror:2
        dpp_step<0x124>(bv, bi);   // row_ror:4
        dpp_step<0x128>(bv, bi);   // row_ror:8
        {
            float ov = __shfl_xor(bv, 16);
            int   oi = __shfl_xor(bi, 16);
            if (ov > bv || (ov == bv && oi < bi)) { bv = ov; bi = oi; }
        }
        {
            float ov = __shfl_xor(bv, 32);
            int   oi = __shfl_xor(bi, 32);
            if (ov > bv || (ov == bv && oi < bi)) { bv = ov; bi = oi; }
        }
        int j = bi;                           // identical on all lanes
        float4 c = ptsL[j];                   // uniform-address LDS broadcast
        if (t == 0) { cbuf[s*3+0] = c.x; cbuf[s*3+1] = c.y; cbuf[s*3+2] = c.z; }
        // fused distance update + local argmax (b128 point reads, dl in regs)
        bv = -1.0f; bi = 0;
        #pragma unroll
        for (int q = 0; q < 32; q++) {
            int n = t + q*64;
            float4 p = ptsL[n];
            float nd = fminf(dl[q], d2s(p.x,p.y,p.z, c.x,c.y,c.z));
            dl[q] = nd;
            if (nd > bv) { bv = nd; bi = n; }
        }
    }
    #pragma unroll
    for (int e = 0; e < 3; e++)
        centersWs[(size_t)b*NS*3 + t + e*64] = cbuf[t + e*64];
}

// ---------------- fused ball query + MLP(3->64->128->512) + masked max, no-h2s ----------------
// LDS map (37392 B):
//   @0     16 KB : layer1 h1s [k][j] swz (k&7)<<4; layer3 bufs for chunks t%4==2 (@0), t%4==3 (@8192)
//   @16384 16 KB : layer3 bufs for chunks t%4==0 (@16384), t%4==1 (@24576); redf[4][512] @16384 after loop
//   @32768 2 KB  : nbL int[4][128]  (scan)  /  relL f32[128][4] (after)
//   @34816 512 B : b2s
//   @35328 2 KB  : b3s
//   @37376 16 B  : cntW4
__global__ __launch_bounds__(256, 4) void ball_mlp_kernel(
    const float* __restrict__ pos,
    const float* __restrict__ W1, const float* __restrict__ b1,
    const float* __restrict__ b2, const float* __restrict__ b3,
    const __hip_bfloat16* __restrict__ W2Tp,
    const __hip_bfloat16* __restrict__ W3Tp,
    const float* __restrict__ centersWs,
    float* __restrict__ out,
    __hip_bfloat16* __restrict__ gAb)
{
    __shared__ char smem[37392];
    char*  h1s  = smem;
    float* relL = (float*)(smem + 32768);
    int*   nbL  = (int*)(smem + 32768);
    float* b2s  = (float*)(smem + 34816);
    float* b3s  = (float*)(smem + 35328);
    int*   cntW4= (int*)(smem + 37376);

    const short* W2T  = (const short*)W2Tp;
    const char*  W3Tb = (const char*)W3Tp;

    int r = blockIdx.x, b = r >> 6, tid = threadIdx.x;
    int l = tid & 63, w = tid >> 6;
    int l31 = l & 31;
    int hsel = l >> 5;
    int jsel8 = hsel * 8;
    int colsel = hsel * 16;

#define STAGE_W3(CH, DST)                                                                              \
    {                                                                                                  \
        const char* _s = W3Tb + (CH)*8192 + w*2048 + l*16;                                             \
        char* _d = (DST) + w*2048;                                                                     \
        __builtin_amdgcn_global_load_lds((const __attribute__((address_space(1))) void*)(_s),          \
                                         (__attribute__((address_space(3))) void*)(_d), 16, 0, 0);     \
        __builtin_amdgcn_global_load_lds((const __attribute__((address_space(1))) void*)(_s + 1024),   \
                                         (__attribute__((address_space(3))) void*)(_d + 1024), 16, 0, 0); \
    }

    // chunk t lives in buf at smem + 8192*((t+2)&3): chunks 0,1 -> dedicated region, stage NOW
    STAGE_W3(0, smem + 16384);
    STAGE_W3(1, smem + 24576);

    float cx = centersWs[r*3+0], cy = centersWs[r*3+1], cz = centersWs[r*3+2];

    // ---- ball query: wave w scans points [w*512, w*512+512), ordered compaction
    const float* pb = pos + (size_t)b * NP * 3;
    {
        int myCnt = 0;
        #pragma unroll
        for (int c = 0; c < 8; c++) {
            int n = w*512 + c*64 + l;
            float x = pb[n*3+0], y = pb[n*3+1], z = pb[n*3+2];
            bool in = d2s(cx,cy,cz, x,y,z) < 0.04f;
            unsigned long long m = __ballot(in);
            int before = __popcll(m & ((1ull << l) - 1ull));
            int p = myCnt + before;
            if (in && p < NK) nbL[w*NK + p] = n;
            myCnt += (int)__popcll(m);
        }
        if (l == 0) cntW4[w] = myCnt;
    }
    // stage b3 -> LDS while scan settles
    b3s[tid] = b3[tid];
    b3s[tid + 256] = b3[tid + 256];
    __syncthreads();

    int c0 = cntW4[0], c1 = cntW4[1], c2 = cntW4[2], c3 = cntW4[3];
    int cnt = c0 + c1 + c2 + c3;
    cnt = cnt > NK ? NK : cnt;

    int nv = 0;
    if (tid < NK) {
        bool valid = tid < cnt;
        int seg = 0, off = 0;
        if (tid >= c0)           { seg = 1; off = c0; }
        if (tid >= c0 + c1)      { seg = 2; off = c0 + c1; }
        if (tid >= c0 + c1 + c2) { seg = 3; off = c0 + c1 + c2; }
        if (valid) nv = nbL[seg*NK + (tid - off)];
        out[XIDX_OFF + r*NK + tid] = valid ? (float)(nv + b*NP) : -1.0f;
        out[YIDX_OFF + r*NK + tid] = valid ? (float)r : -1.0f;
    }
    __syncthreads();          // nbL reads complete before relL overwrite

    if (tid < NK) {
        const float* pp = pb + (size_t)nv*3;
        relL[tid*4+0] = pp[0] - cx;
        relL[tid*4+1] = pp[1] - cy;
        relL[tid*4+2] = pp[2] - cz;
        relL[tid*4+3] = 0.0f;
        b2s[tid] = b2[tid];
    }
    __syncthreads();

    // ---- layer 1 (VALU): h1[k][j] = leaky(rel[k]·W1[:,j] + b1[j])
    {
        int jg = (tid & 15) * 4;
        float4 w0 = *(const float4*)&W1[jg];
        float4 w1 = *(const float4*)&W1[64 + jg];
        float4 w2 = *(const float4*)&W1[128 + jg];
        float4 bb = *(const float4*)&b1[jg];
        #pragma unroll
        for (int e = 0; e < 8; e++) {
            int k = (tid >> 4) + e*16;
            float4 r4 = *(const float4*)&relL[k*4];
            s4 pk;
            pk[0] = (short)bf16u(leaky(bb.x + r4.x*w0.x + r4.y*w1.x + r4.z*w2.x));
            pk[1] = (short)bf16u(leaky(bb.y + r4.x*w0.y + r4.y*w1.y + r4.z*w2.y));
            pk[2] = (short)bf16u(leaky(bb.z + r4.x*w0.z + r4.y*w1.z + r4.z*w2.z));
            pk[3] = (short)bf16u(leaky(bb.w + r4.x*w0.w + r4.y*w1.w + r4.z*w2.w));
            *(s4*)(h1s + k*128 + ((jg*2) ^ ((k&7)<<4))) = pk;
        }
    }
    __syncthreads();

    // ---- layer 2 (MFMA): wave w computes D2[i][k] for ALL i, k = w*32 + l31.
    // C-regs repacked in-register (cvt_pk + permlane32_swap) into layer3 A-frags a3[8].
    short8 a3[8];
    {
        int kcol = w*32 + l31;
        short8 bh[4];
        #pragma unroll
        for (int ks = 0; ks < 4; ks++) {
            int bc = ks*32 + colsel;
            bh[ks] = *(short8*)(h1s + kcol*128 + (bc ^ ((kcol&7)<<4)));
        }
        #pragma unroll
        for (int it = 0; it < 4; it++) {
            short8 aWf[4];
            #pragma unroll
            for (int ks = 0; ks < 4; ks++)
                aWf[ks] = *(const short8*)(W2T + (it*32 + l31)*64 + ks*16 + jsel8);
            f32x16 acc;
            #pragma unroll
            for (int q = 0; q < 16; q++) acc[q] = 0.f;
            #pragma unroll
            for (int ks = 0; ks < 4; ks++)
                acc = __builtin_amdgcn_mfma_f32_32x32x16_bf16(aWf[ks], bh[ks], acc, 0, 0, 0);
            // bias + leaky: acc[reg] holds i = it*32 + 4*hsel + (reg&3) + 8*(reg>>2)
            int ibase = it*32 + 4*hsel;
            #pragma unroll
            for (int g = 0; g < 4; g++) {
                float4 bb = *(const float4*)&b2s[ibase + g*8];
                acc[g*4+0] = leaky(acc[g*4+0] + bb.x);
                acc[g*4+1] = leaky(acc[g*4+1] + bb.y);
                acc[g*4+2] = leaky(acc[g*4+2] + bb.z);
                acc[g*4+3] = leaky(acc[g*4+3] + bb.w);
            }
            // repack: regs hf*8+0..7 -> frag 2it+hf (i = (2it+hf)*16 + jsel8 + 0..7 per lane)
            #pragma unroll
            for (int hf = 0; hf < 2; hf++) {
                unsigned A0 = cvtpk(acc[hf*8+0], acc[hf*8+1]);
                unsigned A1 = cvtpk(acc[hf*8+2], acc[hf*8+3]);
                unsigned B0 = cvtpk(acc[hf*8+4], acc[hf*8+5]);
                unsigned B1 = cvtpk(acc[hf*8+6], acc[hf*8+7]);
                plswap(A0, B0);
                plswap(A1, B1);
                union { unsigned u[4]; short8 s; } f;
                f.u[0] = A0; f.u[1] = A1; f.u[2] = B0; f.u[3] = B1;
                a3[2*it + hf] = f.s;
            }
        }
    }
    __syncthreads();     // all h1s reads done -> h1s region becomes W3 bufs

    // stage chunks 2,3 into h1s region: (2+2)&3=0 -> @0, (3+2)&3=1 -> @8192
    STAGE_W3(2, smem);
    STAGE_W3(3, smem + 8192);

    // ---- layer 3: 16 chunks of 32 cols, 4-buffer pipeline, one barrier/chunk, max in regs
    int kb0 = w*32 + 4*hsel;
    float mred[16];
    #pragma unroll
    for (int t = 0; t < 16; t++) {
        if (t <= 13)      { asm volatile("s_waitcnt vmcnt(4)" ::: "memory"); }
        else if (t == 14) { asm volatile("s_waitcnt vmcnt(2)" ::: "memory"); }
        else              { asm volatile("s_waitcnt vmcnt(0)" ::: "memory"); }
        __builtin_amdgcn_sched_barrier(0);
        __builtin_amdgcn_s_barrier();
        __builtin_amdgcn_sched_barrier(0);

        if (t >= 1 && t + 3 < 16) {
            char* nbuf = smem + 8192*((t+1)&3);     // chunk t+3's buf = (t+5)&3 = (t+1)&3, freed at this barrier
            STAGE_W3(t+3, nbuf);
        }
        __builtin_amdgcn_sched_barrier(0);

        char* buf = smem + 8192*((t+2)&3);
        f32x16 acc;
        #pragma unroll
        for (int q = 0; q < 16; q++) acc[q] = 0.f;
        #pragma unroll
        for (int ks = 0; ks < 8; ks++) {
            int bc = ks*32 + colsel;
            short8 bv = *(short8*)(buf + l31*256 + (bc ^ ((l31&15)<<4)));
            acc = __builtin_amdgcn_mfma_f32_32x32x16_bf16(a3[ks], bv, acc, 0, 0, 0);
        }
        float m = -INFINITY;
        #pragma unroll
        for (int reg = 0; reg < 16; reg++) {
            int kloc = (reg&3) + 8*(reg>>2);
            if (kb0 + kloc < cnt) m = fmaxf(m, acc[reg]);
        }
        m = fmaxf(m, __shfl_xor(m, 32));
        mred[t] = m;
        __builtin_amdgcn_sched_barrier(0);
    }

    // ---- final: dump per-wave partials (bufs for chunks <=13 are dead), reduce, write gAb
    float* redf = (float*)(smem + 16384);
    if (l < 32) {
        #pragma unroll
        for (int t = 0; t < 16; t++)
            redf[w*512 + t*32 + l31] = mred[t];
    }
    __syncthreads();
    #pragma unroll
    for (int e = 0; e < 2; e++) {
        int c = tid + e*256;
        float m = fmaxf(fmaxf(redf[c], redf[512 + c]), fmaxf(redf[1024 + c], redf[1536 + c]));
        gAb[(size_t)r*GA_LD + c] = __float2bfloat16(leaky(m + b3s[c]));
    }
    if (tid < 64) {
        float v = 0.0f;
        if (tid == 0) v = cx; else if (tid == 1) v = cy; else if (tid == 2) v = cz;
        gAb[(size_t)r*GA_LD + 512 + tid] = __float2bfloat16(v);
    }
#undef STAGE_W3
}

// ---------------- FC1 (MFMA): g2b = leaky(gAb[2048,576] @ W4T' + b4), N=512 ----------------
__global__ __launch_bounds__(256) void fc1_kernel(const __hip_bfloat16* __restrict__ gAb,
                                                  const __hip_bfloat16* __restrict__ W4T,
                                                  const float* __restrict__ b4,
                                                  __hip_bfloat16* __restrict__ g2b)
{
    __shared__ char smem[16384];
    char* As = smem;            // [64 rows][64 k] bf16, swz ((row&7)<<4)
    char* Bs = smem + 8192;     // [64 cols][64 k] bf16, swz

    int bx = blockIdx.x & 7;    // N tile (512/64)
    int by = blockIdx.x >> 3;   // M tile (2048/64)
    int tid = threadIdx.x;
    int l = tid & 63, w = tid >> 6;
    int wm = w & 1, wn = w >> 1;
    int colsel = (l >> 5) * 16;

    f32x16 acc;
    #pragma unroll
    for (int q = 0; q < 16; q++) acc[q] = 0.f;

    int ra = wm*32 + (l & 31);
    int rn = wn*32 + (l & 31);

    for (int kb = 0; kb < GA_LD; kb += 64) {
        #pragma unroll
        for (int it = 0; it < 2; it++) {
            int e = it*256 + tid;            // 0..511
            int row = e >> 3, seg = e & 7;
            short8 va = *(const short8*)(gAb + (size_t)(by*64 + row)*GA_LD + kb + seg*8);
            *(short8*)(As + row*128 + ((seg*16) ^ ((row&7)<<4))) = va;
            short8 vb = *(const short8*)(W4T + (size_t)(bx*64 + row)*GA_LD + kb + seg*8);
            *(short8*)(Bs + row*128 + ((seg*16) ^ ((row&7)<<4))) = vb;
        }
        __syncthreads();
        #pragma unroll
        for (int ks = 0; ks < 4; ks++) {
            int bc = ks*32 + colsel;
            short8 av = *(short8*)(As + ra*128 + (bc ^ ((ra&7)<<4)));
            short8 bv = *(short8*)(Bs + rn*128 + (bc ^ ((rn&7)<<4)));
            acc = __builtin_amdgcn_mfma_f32_32x32x16_bf16(av, bv, acc, 0, 0, 0);
        }
        __syncthreads();
    }

    int col = bx*64 + wn*32 + (l & 31);
    float bcol = b4[col];
    int rbase = by*64 + wm*32 + 4*(l>>5);
    #pragma unroll
    for (int reg = 0; reg < 16; reg++) {
        int row = rbase + (reg&3) + 8*(reg>>2);
        g2b[(size_t)row*512 + col] = __float2bfloat16(leaky(acc[reg] + bcol));
    }
}

// ---------------- FC2 (MFMA): out = g2b @ W5T' + b5; mean | std=exp(0.5 lv) ----------------
__global__ __launch_bounds__(256) void fc2_kernel(const __hip_bfloat16* __restrict__ g2b,
                                                  const __hip_bfloat16* __restrict__ W5T,
                                                  const float* __restrict__ b5,
                                                  float* __restrict__ out)
{
    __shared__ char smem[16384];
    char* As = smem;
    char* Bs = smem + 8192;

    int bx = blockIdx.x & 15;   // N tile (1024/64)
    int by = blockIdx.x >> 4;   // M tile (2048/64)
    int tid = threadIdx.x;
    int l = tid & 63, w = tid >> 6;
    int wm = w & 1, wn = w >> 1;
    int colsel = (l >> 5) * 16;

    f32x16 acc;
    #pragma unroll
    for (int q = 0; q < 16; q++) acc[q] = 0.f;

    int ra = wm*32 + (l & 31);
    int rn = wn*32 + (l & 31);

    for (int kb = 0; kb < 512; kb += 64) {
        #pragma unroll
        for (int it = 0; it < 2; it++) {
            int e = it*256 + tid;
            int row = e >> 3, seg = e & 7;
            short8 va = *(const short8*)(g2b + (size_t)(by*64 + row)*512 + kb + seg*8);
            *(short8*)(As + row*128 + ((seg*16) ^ ((row&7)<<4))) = va;
            short8 vb = *(const short8*)(W5T + (size_t)(bx*64 + row)*512 + kb + seg*8);
            *(short8*)(Bs + row*128 + ((seg*16) ^ ((row&7)<<4))) = vb;
        }
        __syncthreads();
        #pragma unroll
        for (int ks = 0; ks < 4; ks++) {
            int bc = ks*32 + colsel;
            short8 av = *(short8*)(As + ra*128 + (bc ^ ((ra&7)<<4)));
            short8 bv = *(short8*)(Bs + rn*128 + (bc ^ ((rn&7)<<4)));
            acc = __builtin_amdgcn_mfma_f32_32x32x16_bf16(av, bv, acc, 0, 0, 0);
        }
        __syncthreads();
    }

    int col = bx*64 + wn*32 + (l & 31);
    float bcol = b5[col];
    int rbase = by*64 + wm*32 + 4*(l>>5);
    #pragma unroll
    for (int reg = 0; reg < 16; reg++) {
        int row = rbase + (reg&3) + 8*(reg>>2);
        float v = acc[reg] + bcol;
        if (col < 512) {
            out[MEAN_OFF + (size_t)row*512 + col] = v;
        } else {
            out[STD_OFF + (size_t)row*512 + (col - 512)] = expf(0.5f*v);
        }
    }
}

extern "C" void kernel_launch(void* const* d_in, const int* in_sizes, int n_in,
                              void* d_out, int out_size, void* d_ws, size_t ws_size,
                              hipStream_t stream) {
    const float* pos = (const float*)d_in[0];
    const float* W1  = (const float*)d_in[2];
    const float* b1  = (const float*)d_in[3];
    const float* W2  = (const float*)d_in[4];
    const float* b2  = (const float*)d_in[5];
    const float* W3  = (const float*)d_in[6];
    const float* b3  = (const float*)d_in[7];
    const float* W4  = (const float*)d_in[8];
    const float* b4  = (const float*)d_in[9];
    const float* W5  = (const float*)d_in[10];
    const float* b5  = (const float*)d_in[11];
    float* out = (float*)d_out;

    char* ws = (char*)d_ws;
    float* centersWs = (float*)(ws);                          // 24576 B
    __hip_bfloat16* gAb = (__hip_bfloat16*)(ws + 1081344);    // 2048*576*2 = 2359296
    __hip_bfloat16* g2b = (__hip_bfloat16*)(ws + 3440640);    // 2048*512*2 = 2097152
    __hip_bfloat16* W2T = (__hip_bfloat16*)(ws + 5537792);    // 16 KB
    __hip_bfloat16* W3T = (__hip_bfloat16*)(ws + 5554176);    // 128 KB
    __hip_bfloat16* W4T = (__hip_bfloat16*)(ws + 5685248);    // 576 KB
    __hip_bfloat16* W5T = (__hip_bfloat16*)(ws + 6275072);    // 1 MB -> ends 7323648

    hipLaunchKernelGGL(fps_prep_kernel, dim3(NB + 217), dim3(256), 0, stream,
                       pos, centersWs, W2, W3, W4, W5, W2T, W3T, W4T, W5T);
    hipLaunchKernelGGL(ball_mlp_kernel, dim3(NB*NS), dim3(256), 0, stream,
                       pos, W1,b1, b2,b3, W2T, W3T, centersWs, out, gAb);
    hipLaunchKernelGGL(fc1_kernel, dim3(256), dim3(256), 0, stream, gAb, W4T, b4, g2b);
    hipLaunchKernelGGL(fc2_kernel, dim3(512), dim3(256), 0, stream, g2b, W5T, b5, out);
}